// Round 1
// baseline (2431.157 us; speedup 1.0000x reference)
//
#include <hip/hip_runtime.h>
#include <cstddef>

// TransitionDown: B=16 clouds, P=4096 pts, S=1024 fps samples, K=16 knn,
// IN_F=256, OUT_F=512.
// Pipeline:
//   L1 fused: blocks[0,16)   FPS per cloud (np-bitwise fp32, no FMA)
//             blocks[16,1040) MLP GEMM fp32 -> h bf16 (hidden under FPS)
//             blocks[1040,2064) xx[i] = ||features_i||^2
//   L2: BN partial sums over h   L3: BN finalize -> scale/shift
//   L4: KNN fp32 fused top-16 (tile 32q x 256c, micro 4x8)
//   L5: gather + BN + ReLU + max over K

#define TD_B   16
#define TD_P   4096
#define TD_S   1024
#define TD_K   16
#define TD_INF 256
#define TD_OUTF 512

__device__ __forceinline__ unsigned short f2bf(float x) {
    unsigned u = __float_as_uint(x);
    unsigned r = (u + 0x7fffu + ((u >> 16) & 1u)) >> 16;   // RNE
    return (unsigned short)r;
}

struct FpsSm {
    float sx[TD_P]; float sy[TD_P]; float sz[TD_P];
    int   sel[TD_S];
    float rv[8]; int ri[8]; int cur;
};
struct GemmSm {
    float As[16 * 260];   // [k][m], m-stride 260 (pad: 2-way write conflicts only)
    float Bs[16 * 128];   // [k][n]
};
union SmU { FpsSm f; GemmSm g; };

__global__ __launch_bounds__(512)
void td_fused(const float* __restrict__ feat, const float* __restrict__ pos,
              const float* __restrict__ W, const float* __restrict__ bias,
              unsigned short* __restrict__ H, float* __restrict__ XX,
              int* __restrict__ FPSI, float* __restrict__ outP,
              float* __restrict__ outB) {
    __shared__ SmU sm;
    const int bx = blockIdx.x;
    const int t  = threadIdx.x;

    if (bx < 16) {
        // ---------------- FPS: one block per cloud, np-bitwise fp32 ----------
        __builtin_amdgcn_s_setprio(2);   // win issue arbitration vs GEMM waves
        const int b = bx;
        float px[8], py[8], pz[8], md[8];
#pragma unroll
        for (int j = 0; j < 8; ++j) {
            int p = j * 512 + t;
            const float* pp = pos + (size_t)(b * TD_P + p) * 3;
            float x = pp[0], y = pp[1], z = pp[2];
            px[j] = x; py[j] = y; pz[j] = z;
            sm.f.sx[p] = x; sm.f.sy[p] = y; sm.f.sz[p] = z;
            md[j] = __builtin_inff();
        }
        __syncthreads();
        int last = 0;
        for (int s = 0;; ++s) {
            if (t == 0) sm.f.sel[s] = last;
            if (s == TD_S - 1) break;
            float lx = sm.f.sx[last], ly = sm.f.sy[last], lz = sm.f.sz[last];
            float bv = -1.0f; int bi = 0x7fffffff;
#pragma unroll
            for (int j = 0; j < 8; ++j) {
                // exact np order: sub, sq, sq, sq, add, add, min (no contraction)
                float dx = __fsub_rn(px[j], lx);
                float dy = __fsub_rn(py[j], ly);
                float dz = __fsub_rn(pz[j], lz);
                float d  = __fadd_rn(__fadd_rn(__fmul_rn(dx, dx), __fmul_rn(dy, dy)),
                                     __fmul_rn(dz, dz));
                float m  = fminf(md[j], d);
                md[j] = m;
                if (m > bv) { bv = m; bi = j * 512 + t; }   // ascending p: ties->low idx
            }
#pragma unroll
            for (int off = 32; off > 0; off >>= 1) {
                float ov = __shfl_down(bv, off, 64);
                int   oi = __shfl_down(bi, off, 64);
                if (ov > bv || (ov == bv && oi < bi)) { bv = ov; bi = oi; }
            }
            if ((t & 63) == 0) { int w = t >> 6; sm.f.rv[w] = bv; sm.f.ri[w] = bi; }
            __syncthreads();
            if (t == 0) {
                float cv = sm.f.rv[0]; int ci = sm.f.ri[0];
#pragma unroll
                for (int w = 1; w < 8; ++w) {
                    float v2 = sm.f.rv[w]; int i2 = sm.f.ri[w];
                    if (v2 > cv || (v2 == cv && i2 < ci)) { cv = v2; ci = i2; }
                }
                sm.f.cur = ci;
            }
            __syncthreads();
            last = sm.f.cur;
        }
        __syncthreads();
        for (int s = t; s < TD_S; s += 512) {
            int li = sm.f.sel[s];
            int og = b * TD_S + s;
            outP[og * 3 + 0] = sm.f.sx[li];
            outP[og * 3 + 1] = sm.f.sy[li];
            outP[og * 3 + 2] = sm.f.sz[li];
            outB[og] = (float)b;
            FPSI[og] = b * TD_P + li;   // global row index
        }
    } else if (bx < 16 + 1024) {
        // ---------------- MLP GEMM: 256x128 tile, 512 thr, 8x8 micro ---------
        const int gb = bx - 16;
        const int mb = gb >> 2, nb = gb & 3;
        const int tm = t >> 4, tn = t & 15;
        float acc[8][8];
#pragma unroll
        for (int i = 0; i < 8; ++i)
#pragma unroll
            for (int j = 0; j < 8; ++j) acc[i][j] = 0.0f;
        float* As = sm.g.As;
        float* Bs = sm.g.Bs;
        for (int kc = 0; kc < 16; ++kc) {
#pragma unroll
            for (int p2 = 0; p2 < 2; ++p2) {
                int f4 = t + 512 * p2;
                int r = f4 >> 2, c4 = f4 & 3;
                float4 v = *(const float4*)&feat[(size_t)(mb * 256 + r) * 256 + kc * 16 + c4 * 4];
                As[(c4 * 4 + 0) * 260 + r] = v.x;
                As[(c4 * 4 + 1) * 260 + r] = v.y;
                As[(c4 * 4 + 2) * 260 + r] = v.z;
                As[(c4 * 4 + 3) * 260 + r] = v.w;
            }
            {
                int kk = t >> 5, n4 = t & 31;
                float4 v = *(const float4*)&W[(size_t)(kc * 16 + kk) * 512 + nb * 128 + n4 * 4];
                *(float4*)&Bs[kk * 128 + n4 * 4] = v;
            }
            __syncthreads();
#pragma unroll
            for (int kk = 0; kk < 16; ++kk) {
                float4 a0 = *(float4*)&As[kk * 260 + tm * 8];
                float4 a1 = *(float4*)&As[kk * 260 + tm * 8 + 4];
                float4 b0 = *(float4*)&Bs[kk * 128 + tn * 8];
                float4 b1 = *(float4*)&Bs[kk * 128 + tn * 8 + 4];
                float av[8] = {a0.x, a0.y, a0.z, a0.w, a1.x, a1.y, a1.z, a1.w};
                float bv2[8] = {b0.x, b0.y, b0.z, b0.w, b1.x, b1.y, b1.z, b1.w};
#pragma unroll
                for (int i = 0; i < 8; ++i)
#pragma unroll
                    for (int j = 0; j < 8; ++j)
                        acc[i][j] = fmaf(av[i], bv2[j], acc[i][j]);
            }
            __syncthreads();
        }
        float4 bb0 = *(const float4*)&bias[nb * 128 + tn * 8];
        float4 bb1 = *(const float4*)&bias[nb * 128 + tn * 8 + 4];
        float bsv[8] = {bb0.x, bb0.y, bb0.z, bb0.w, bb1.x, bb1.y, bb1.z, bb1.w};
#pragma unroll
        for (int i = 0; i < 8; ++i) {
            int row = mb * 256 + tm * 8 + i;
            uint4 pk;
            pk.x = (unsigned)f2bf(acc[i][0] + bsv[0]) | ((unsigned)f2bf(acc[i][1] + bsv[1]) << 16);
            pk.y = (unsigned)f2bf(acc[i][2] + bsv[2]) | ((unsigned)f2bf(acc[i][3] + bsv[3]) << 16);
            pk.z = (unsigned)f2bf(acc[i][4] + bsv[4]) | ((unsigned)f2bf(acc[i][5] + bsv[5]) << 16);
            pk.w = (unsigned)f2bf(acc[i][6] + bsv[6]) | ((unsigned)f2bf(acc[i][7] + bsv[7]) << 16);
            *(uint4*)&H[(size_t)row * 512 + nb * 128 + tn * 8] = pk;
        }
    } else {
        // ---------------- xx[i] = ||features_i||^2 ---------------------------
        const int xb = bx - 1040;
        const int w = t >> 6, lane = t & 63;
#pragma unroll
        for (int it = 0; it < 8; ++it) {
            int r = xb * 64 + w * 8 + it;
            float4 v = *(const float4*)&feat[(size_t)r * 256 + lane * 4];
            float s = v.x * v.x + v.y * v.y + v.z * v.z + v.w * v.w;
#pragma unroll
            for (int off = 32; off > 0; off >>= 1) s += __shfl_down(s, off, 64);
            if (lane == 0) XX[r] = s;
        }
    }
}

__global__ __launch_bounds__(256)
void td_stats(const unsigned short* __restrict__ H, float* __restrict__ P1,
              float* __restrict__ P2) {
    const int rb = blockIdx.x, t = threadIdx.x;
    float s1a = 0, s2a = 0, s1b = 0, s2b = 0;
    for (int r = 0; r < 128; ++r) {
        const unsigned* hp = (const unsigned*)(H + (size_t)(rb * 128 + r) * 512);
        unsigned u = hp[t];
        float lo = __uint_as_float(u << 16);
        float hi = __uint_as_float(u & 0xffff0000u);
        s1a += lo; s2a = fmaf(lo, lo, s2a);
        s1b += hi; s2b = fmaf(hi, hi, s2b);
    }
    P1[rb * 512 + 2 * t] = s1a; P1[rb * 512 + 2 * t + 1] = s1b;
    P2[rb * 512 + 2 * t] = s2a; P2[rb * 512 + 2 * t + 1] = s2b;
}

__global__ __launch_bounds__(512)
void td_bnfin(const float* __restrict__ P1, const float* __restrict__ P2,
              const float* __restrict__ gamma, const float* __restrict__ beta,
              float* __restrict__ SS) {
    const int ch = threadIdx.x;
    float s1 = 0, s2 = 0;
    for (int rb = 0; rb < 512; ++rb) { s1 += P1[rb * 512 + ch]; s2 += P2[rb * 512 + ch]; }
    const float invN = 1.0f / 65536.0f;
    float mu  = s1 * invN;
    float var = s2 * invN - mu * mu;
    float sc  = gamma[ch] * (1.0f / sqrtf(var + 1e-5f));
    float sh  = beta[ch] - mu * sc;
    SS[ch] = sc; SS[512 + ch] = sh;
}

// KNN: 512 blocks (16 clouds x 32 q-tiles of 32), 256 thr.
// Block tile 32q x 256c, K chunked by 32; micro-tile 4q x 8c per thread.
// Dt/merge arrays alias Xs region; fused per-thread top-16 + final merge.
__global__ __launch_bounds__(256)
void td_knn(const float* __restrict__ feat, const float* __restrict__ XX,
            const int* __restrict__ FPSI, int* __restrict__ NN) {
    __shared__ float Xs[32 * 260];   // Xs[k][c] / Dt[q][c] / merge d+idx
    __shared__ float Qs[32 * 36];    // Qs[k][q]
    __shared__ int   qrl[32];
    __shared__ float qqL[32];
    const int bx = blockIdx.x, t = threadIdx.x;
    const int b = bx >> 5, qt = bx & 31;
    const int cb = b * TD_P;
    const int tq = t >> 5, tc = t & 31;   // compute mapping
    const int qs = t >> 3, ts = t & 7;    // selection mapping

    if (t < 32) {
        int gr = FPSI[b * TD_S + qt * 32 + t];
        qrl[t] = gr; qqL[t] = XX[gr];
    }
    float sd[16]; int si[16];
#pragma unroll
    for (int r = 0; r < 16; ++r) { sd[r] = __builtin_inff(); si[r] = 0x7fffffff; }
    __syncthreads();

    for (int ct = 0; ct < 16; ++ct) {
        float acc[4][8];
#pragma unroll
        for (int qi = 0; qi < 4; ++qi)
#pragma unroll
            for (int cc = 0; cc < 8; ++cc) acc[qi][cc] = 0.0f;
        for (int kc = 0; kc < 8; ++kc) {
            __syncthreads();   // protects Xs reuse (prev compute / prev Dt reads)
            {
                int q = t >> 3, f4i = t & 7;
                float4 v = *(const float4*)&feat[(size_t)qrl[q] * 256 + kc * 32 + f4i * 4];
                Qs[(f4i * 4 + 0) * 36 + q] = v.x;
                Qs[(f4i * 4 + 1) * 36 + q] = v.y;
                Qs[(f4i * 4 + 2) * 36 + q] = v.z;
                Qs[(f4i * 4 + 3) * 36 + q] = v.w;
            }
#pragma unroll
            for (int p2 = 0; p2 < 8; ++p2) {
                int f4 = t + 256 * p2;
                int c = f4 >> 3, f4i = f4 & 7;
                float4 v = *(const float4*)&feat[(size_t)(cb + ct * 256 + c) * 256 + kc * 32 + f4i * 4];
                Xs[(f4i * 4 + 0) * 260 + c] = v.x;
                Xs[(f4i * 4 + 1) * 260 + c] = v.y;
                Xs[(f4i * 4 + 2) * 260 + c] = v.z;
                Xs[(f4i * 4 + 3) * 260 + c] = v.w;
            }
            __syncthreads();
#pragma unroll
            for (int kk = 0; kk < 32; ++kk) {
                float4 a  = *(float4*)&Qs[kk * 36 + tq * 4];
                float4 b0 = *(float4*)&Xs[kk * 260 + tc * 8];
                float4 b1 = *(float4*)&Xs[kk * 260 + tc * 8 + 4];
                float av[4]  = {a.x, a.y, a.z, a.w};
                float bv2[8] = {b0.x, b0.y, b0.z, b0.w, b1.x, b1.y, b1.z, b1.w};
#pragma unroll
                for (int qi = 0; qi < 4; ++qi)
#pragma unroll
                    for (int cc = 0; cc < 8; ++cc)
                        acc[qi][cc] = fmaf(av[qi], bv2[cc], acc[qi][cc]);
            }
        }
        __syncthreads();   // all Xs reads done; safe to overwrite as Dt
        float4 x0 = *(const float4*)&XX[cb + ct * 256 + tc * 8];
        float4 x1 = *(const float4*)&XX[cb + ct * 256 + tc * 8 + 4];
        float xv[8] = {x0.x, x0.y, x0.z, x0.w, x1.x, x1.y, x1.z, x1.w};
#pragma unroll
        for (int qi = 0; qi < 4; ++qi) {
            int q = tq * 4 + qi;
            float qq = qqL[q];
            float4 d0, d1;
            d0.x = (qq - 2.0f * acc[qi][0]) + xv[0];
            d0.y = (qq - 2.0f * acc[qi][1]) + xv[1];
            d0.z = (qq - 2.0f * acc[qi][2]) + xv[2];
            d0.w = (qq - 2.0f * acc[qi][3]) + xv[3];
            d1.x = (qq - 2.0f * acc[qi][4]) + xv[4];
            d1.y = (qq - 2.0f * acc[qi][5]) + xv[5];
            d1.z = (qq - 2.0f * acc[qi][6]) + xv[6];
            d1.w = (qq - 2.0f * acc[qi][7]) + xv[7];
            *(float4*)&Xs[q * 260 + tc * 8]     = d0;
            *(float4*)&Xs[q * 260 + tc * 8 + 4] = d1;
        }
        __syncthreads();
        // per-thread running top-16 over its stripe (ascending idx => ties keep low idx)
        for (int j = 0; j < 32; ++j) {
            int c = ts * 32 + j;
            float d = Xs[qs * 260 + c];
            int idx = ct * 256 + c;
            if (d < sd[15]) {
                sd[15] = d; si[15] = idx;
#pragma unroll
                for (int r = 15; r > 0; --r) {
                    if (sd[r] < sd[r - 1]) {
                        float td2 = sd[r]; sd[r] = sd[r - 1]; sd[r - 1] = td2;
                        int ti = si[r]; si[r] = si[r - 1]; si[r - 1] = ti;
                    }
                }
            }
        }
    }
    __syncthreads();
#pragma unroll
    for (int r = 0; r < 16; ++r) {
        int slot = ts * 16 + r;
        Xs[qs * 130 + slot] = sd[r];
        ((int*)Xs)[4160 + qs * 130 + slot] = si[r];
    }
    __syncthreads();
    if (t < 32) {
        int q = t;
#pragma unroll
        for (int r = 0; r < 16; ++r) { sd[r] = __builtin_inff(); si[r] = 0x7fffffff; }
        for (int m = 0; m < 128; ++m) {
            float d = Xs[q * 130 + m];
            int idx = ((int*)Xs)[4160 + q * 130 + m];
            if (d < sd[15] || (d == sd[15] && idx < si[15])) {
                sd[15] = d; si[15] = idx;
#pragma unroll
                for (int r = 15; r > 0; --r) {
                    bool sw = (sd[r] < sd[r - 1]) || (sd[r] == sd[r - 1] && si[r] < si[r - 1]);
                    if (sw) {
                        float td2 = sd[r]; sd[r] = sd[r - 1]; sd[r - 1] = td2;
                        int ti = si[r]; si[r] = si[r - 1]; si[r - 1] = ti;
                    }
                }
            }
        }
        int og = (b * TD_S + qt * 32 + q) * TD_K;
#pragma unroll
        for (int r = 0; r < 16; ++r) NN[og + r] = cb + si[r];
    }
}

__global__ __launch_bounds__(256)
void td_maxpool(const unsigned short* __restrict__ H, const int* __restrict__ NN,
                const float* __restrict__ SS, float* __restrict__ outF) {
    __shared__ int nbr[16];
    const int g = blockIdx.x, t = threadIdx.x;
    if (t < 16) nbr[t] = NN[g * 16 + t];
    __syncthreads();
    float sc0 = SS[2 * t], sc1 = SS[2 * t + 1];
    float sh0 = SS[512 + 2 * t], sh1 = SS[512 + 2 * t + 1];
    float m0 = 0.0f, m1 = 0.0f;   // relu floor: max_k relu(v) = max(0, max_k v)
#pragma unroll
    for (int k = 0; k < 16; ++k) {
        int row = nbr[k];
        unsigned u = ((const unsigned*)(H + (size_t)row * 512))[t];
        float lo = __uint_as_float(u << 16);
        float hi = __uint_as_float(u & 0xffff0000u);
        m0 = fmaxf(m0, fmaf(sc0, lo, sh0));
        m1 = fmaxf(m1, fmaf(sc1, hi, sh1));
    }
    float2 o; o.x = m0; o.y = m1;
    *(float2*)&outF[(size_t)g * 512 + 2 * t] = o;
}

extern "C" void kernel_launch(void* const* d_in, const int* in_sizes, int n_in,
                              void* d_out, int out_size, void* d_ws, size_t ws_size,
                              hipStream_t stream) {
    const float* feat  = (const float*)d_in[0];
    const float* pos   = (const float*)d_in[1];
    // d_in[2] = batch (int32): unused, value is row/P by construction
    const float* W     = (const float*)d_in[3];
    const float* bias  = (const float*)d_in[4];
    const float* gamma = (const float*)d_in[5];
    const float* beta  = (const float*)d_in[6];

    char* ws = (char*)d_ws;
    unsigned short* H = (unsigned short*)ws;            // 67,108,864 B  (bf16 h)
    float* XX  = (float*)(ws + 67108864);               //    262,144 B
    int*   FPSI= (int*)  (ws + 67371008);               //     65,536 B
    int*   NN  = (int*)  (ws + 67436544);               //  1,048,576 B
    float* P1  = (float*)(ws + 68485120);               //  1,048,576 B
    float* P2  = (float*)(ws + 69533696);               //  1,048,576 B
    float* SS  = (float*)(ws + 70582272);               //      4,096 B

    float* outF = (float*)d_out;
    float* outP = outF + (size_t)TD_B * TD_S * TD_OUTF;   // 8,388,608
    float* outB = outP + (size_t)TD_B * TD_S * 3;         // +49,152

    td_fused  <<<2064, 512, 0, stream>>>(feat, pos, W, bias, H, XX, FPSI, outP, outB);
    td_stats  <<<512, 256, 0, stream>>>(H, P1, P2);
    td_bnfin  <<<1, 512, 0, stream>>>(P1, P2, gamma, beta, SS);
    td_knn    <<<512, 256, 0, stream>>>(feat, XX, FPSI, NN);
    td_maxpool<<<TD_B * TD_S, 256, 0, stream>>>(H, NN, SS, outF);
}

// Round 2
// 1728.928 us; speedup vs baseline: 1.4062x; 1.4062x over previous
//
#include <hip/hip_runtime.h>
#include <cstddef>

// TransitionDown: B=16 clouds, P=4096 pts, S=1024 fps samples, K=16 knn,
// IN_F=256, OUT_F=512.
// Pipeline:
//   L1 fused: blocks[0,16)   FPS per cloud (np-bitwise fp32, no FMA),
//                            1 barrier/step, packed f64 argmax keys
//             blocks[16,1040) MLP GEMM fp32 -> h bf16 (hidden under FPS)
//             blocks[1040,2064) xx[i] = ||features_i||^2
//   L2: BN partial sums over h (128 blocks)   L3: BN finalize -> scale/shift
//   L4: KNN fp32 fused top-16 (tile 32q x 256c, micro 4x8)
//   L5: gather + BN + ReLU + max over K

#define TD_B   16
#define TD_P   4096
#define TD_S   1024
#define TD_K   16
#define TD_INF 256
#define TD_OUTF 512

__device__ __forceinline__ unsigned short f2bf(float x) {
    unsigned u = __float_as_uint(x);
    unsigned r = (u + 0x7fffu + ((u >> 16) & 1u)) >> 16;   // RNE
    return (unsigned short)r;
}

struct FpsSm {
    float sx[TD_P]; float sy[TD_P]; float sz[TD_P];
    int   sel[TD_S];
    double kw[2][8];      // parity-double-buffered per-wave argmax keys
};
struct GemmSm {
    float As[16 * 260];   // [k][m]
    float Bs[16 * 128];   // [k][n]
};
union SmU { FpsSm f; GemmSm g; };

__global__ __launch_bounds__(512)
void td_fused(const float* __restrict__ feat, const float* __restrict__ pos,
              const float* __restrict__ W, const float* __restrict__ bias,
              unsigned short* __restrict__ H, float* __restrict__ XX,
              int* __restrict__ FPSI, float* __restrict__ outP,
              float* __restrict__ outB) {
    __shared__ SmU sm;
    const int bx = blockIdx.x;
    const int t  = threadIdx.x;

    if (bx < 16) {
        // ---------------- FPS: one block per cloud ---------------------------
        // key = double with hi32 = fp32 bits of min_d (>=0 -> positive double,
        // monotone in value), lo32 = ~p  (max => largest d, tie -> lowest p).
        // np-bitwise distance math: sub, sq, sq, sq, add, add, min (no FMA).
        __builtin_amdgcn_s_setprio(2);   // win issue arbitration vs GEMM waves
        const int b = bx;
        const int w = t >> 6;
        float px[8], py[8], pz[8], md[8];
        int ni[8];
#pragma unroll
        for (int j = 0; j < 8; ++j) {
            int p = j * 512 + t;
            const float* pp = pos + (size_t)(b * TD_P + p) * 3;
            float x = pp[0], y = pp[1], z = pp[2];
            px[j] = x; py[j] = y; pz[j] = z;
            sm.f.sx[p] = x; sm.f.sy[p] = y; sm.f.sz[p] = z;
            md[j] = __builtin_inff();
            ni[j] = ~p;
        }
        if (t == 0) sm.f.sel[0] = 0;
        __syncthreads();
        float lx = sm.f.sx[0], ly = sm.f.sy[0], lz = sm.f.sz[0];
        for (int s = 0; s < TD_S - 1; ++s) {
            double kmax = 0.0;
#pragma unroll
            for (int j = 0; j < 8; ++j) {
                float dx = __fsub_rn(px[j], lx);
                float dy = __fsub_rn(py[j], ly);
                float dz = __fsub_rn(pz[j], lz);
                float d  = __fadd_rn(__fadd_rn(__fmul_rn(dx, dx), __fmul_rn(dy, dy)),
                                     __fmul_rn(dz, dz));
                float m  = fminf(md[j], d);
                md[j] = m;
                double k = __hiloint2double(__float_as_int(m), ni[j]);
                kmax = fmax(kmax, k);
            }
#pragma unroll
            for (int off = 32; off > 0; off >>= 1)
                kmax = fmax(kmax, __shfl_xor(kmax, off, 64));
            const int par = s & 1;
            if ((t & 63) == 0) sm.f.kw[par][w] = kmax;
            __syncthreads();
            double gk = sm.f.kw[par][0];
#pragma unroll
            for (int i = 1; i < 8; ++i) gk = fmax(gk, sm.f.kw[par][i]);
            unsigned idx = ~(unsigned)(unsigned long long)__double_as_longlong(gk);
            if (t == 0) sm.f.sel[s + 1] = (int)idx;
            lx = sm.f.sx[idx]; ly = sm.f.sy[idx]; lz = sm.f.sz[idx];
        }
        __syncthreads();
        for (int s = t; s < TD_S; s += 512) {
            int li = sm.f.sel[s];
            int og = b * TD_S + s;
            outP[og * 3 + 0] = sm.f.sx[li];
            outP[og * 3 + 1] = sm.f.sy[li];
            outP[og * 3 + 2] = sm.f.sz[li];
            outB[og] = (float)b;
            FPSI[og] = b * TD_P + li;   // global row index
        }
    } else if (bx < 16 + 1024) {
        // ---------------- MLP GEMM: 256x128 tile, 512 thr, 8x8 micro ---------
        const int gb = bx - 16;
        const int mb = gb >> 2, nb = gb & 3;
        const int tm = t >> 4, tn = t & 15;
        float acc[8][8];
#pragma unroll
        for (int i = 0; i < 8; ++i)
#pragma unroll
            for (int j = 0; j < 8; ++j) acc[i][j] = 0.0f;
        float* As = sm.g.As;
        float* Bs = sm.g.Bs;
        for (int kc = 0; kc < 16; ++kc) {
#pragma unroll
            for (int p2 = 0; p2 < 2; ++p2) {
                int f4 = t + 512 * p2;
                int r = f4 >> 2, c4 = f4 & 3;
                float4 v = *(const float4*)&feat[(size_t)(mb * 256 + r) * 256 + kc * 16 + c4 * 4];
                As[(c4 * 4 + 0) * 260 + r] = v.x;
                As[(c4 * 4 + 1) * 260 + r] = v.y;
                As[(c4 * 4 + 2) * 260 + r] = v.z;
                As[(c4 * 4 + 3) * 260 + r] = v.w;
            }
            {
                int kk = t >> 5, n4 = t & 31;
                float4 v = *(const float4*)&W[(size_t)(kc * 16 + kk) * 512 + nb * 128 + n4 * 4];
                *(float4*)&Bs[kk * 128 + n4 * 4] = v;
            }
            __syncthreads();
#pragma unroll
            for (int kk = 0; kk < 16; ++kk) {
                float4 a0 = *(float4*)&As[kk * 260 + tm * 8];
                float4 a1 = *(float4*)&As[kk * 260 + tm * 8 + 4];
                float4 b0 = *(float4*)&Bs[kk * 128 + tn * 8];
                float4 b1 = *(float4*)&Bs[kk * 128 + tn * 8 + 4];
                float av[8] = {a0.x, a0.y, a0.z, a0.w, a1.x, a1.y, a1.z, a1.w};
                float bv2[8] = {b0.x, b0.y, b0.z, b0.w, b1.x, b1.y, b1.z, b1.w};
#pragma unroll
                for (int i = 0; i < 8; ++i)
#pragma unroll
                    for (int j = 0; j < 8; ++j)
                        acc[i][j] = fmaf(av[i], bv2[j], acc[i][j]);
            }
            __syncthreads();
        }
        float4 bb0 = *(const float4*)&bias[nb * 128 + tn * 8];
        float4 bb1 = *(const float4*)&bias[nb * 128 + tn * 8 + 4];
        float bsv[8] = {bb0.x, bb0.y, bb0.z, bb0.w, bb1.x, bb1.y, bb1.z, bb1.w};
#pragma unroll
        for (int i = 0; i < 8; ++i) {
            int row = mb * 256 + tm * 8 + i;
            uint4 pk;
            pk.x = (unsigned)f2bf(acc[i][0] + bsv[0]) | ((unsigned)f2bf(acc[i][1] + bsv[1]) << 16);
            pk.y = (unsigned)f2bf(acc[i][2] + bsv[2]) | ((unsigned)f2bf(acc[i][3] + bsv[3]) << 16);
            pk.z = (unsigned)f2bf(acc[i][4] + bsv[4]) | ((unsigned)f2bf(acc[i][5] + bsv[5]) << 16);
            pk.w = (unsigned)f2bf(acc[i][6] + bsv[6]) | ((unsigned)f2bf(acc[i][7] + bsv[7]) << 16);
            *(uint4*)&H[(size_t)row * 512 + nb * 128 + tn * 8] = pk;
        }
    } else {
        // ---------------- xx[i] = ||features_i||^2 ---------------------------
        const int xb = bx - 1040;
        const int w = t >> 6, lane = t & 63;
#pragma unroll
        for (int it = 0; it < 8; ++it) {
            int r = xb * 64 + w * 8 + it;
            float4 v = *(const float4*)&feat[(size_t)r * 256 + lane * 4];
            float s = v.x * v.x + v.y * v.y + v.z * v.z + v.w * v.w;
#pragma unroll
            for (int off = 32; off > 0; off >>= 1) s += __shfl_down(s, off, 64);
            if (lane == 0) XX[r] = s;
        }
    }
}

__global__ __launch_bounds__(256)
void td_stats(const unsigned short* __restrict__ H, float* __restrict__ P1,
              float* __restrict__ P2) {
    const int rb = blockIdx.x, t = threadIdx.x;   // 128 blocks x 512 rows
    float s1a = 0, s2a = 0, s1b = 0, s2b = 0;
    for (int r = 0; r < 512; ++r) {
        const unsigned* hp = (const unsigned*)(H + (size_t)(rb * 512 + r) * 512);
        unsigned u = hp[t];
        float lo = __uint_as_float(u << 16);
        float hi = __uint_as_float(u & 0xffff0000u);
        s1a += lo; s2a = fmaf(lo, lo, s2a);
        s1b += hi; s2b = fmaf(hi, hi, s2b);
    }
    P1[rb * 512 + 2 * t] = s1a; P1[rb * 512 + 2 * t + 1] = s1b;
    P2[rb * 512 + 2 * t] = s2a; P2[rb * 512 + 2 * t + 1] = s2b;
}

__global__ __launch_bounds__(512)
void td_bnfin(const float* __restrict__ P1, const float* __restrict__ P2,
              const float* __restrict__ gamma, const float* __restrict__ beta,
              float* __restrict__ SS) {
    const int ch = threadIdx.x;
    float s1 = 0, s2 = 0;
    for (int rb = 0; rb < 128; ++rb) { s1 += P1[rb * 512 + ch]; s2 += P2[rb * 512 + ch]; }
    const float invN = 1.0f / 65536.0f;
    float mu  = s1 * invN;
    float var = s2 * invN - mu * mu;
    float sc  = gamma[ch] * (1.0f / sqrtf(var + 1e-5f));
    float sh  = beta[ch] - mu * sc;
    SS[ch] = sc; SS[512 + ch] = sh;
}

// KNN: 512 blocks (16 clouds x 32 q-tiles of 32), 256 thr.
// Block tile 32q x 256c, K chunked by 32; micro-tile 4q x 8c per thread.
// Dt/merge arrays alias Xs region; fused per-thread top-16 + final merge.
__global__ __launch_bounds__(256)
void td_knn(const float* __restrict__ feat, const float* __restrict__ XX,
            const int* __restrict__ FPSI, int* __restrict__ NN) {
    __shared__ float Xs[32 * 260];   // Xs[k][c] / Dt[q][c] / merge d+idx
    __shared__ float Qs[32 * 36];    // Qs[k][q]
    __shared__ int   qrl[32];
    __shared__ float qqL[32];
    const int bx = blockIdx.x, t = threadIdx.x;
    const int b = bx >> 5, qt = bx & 31;
    const int cb = b * TD_P;
    const int tq = t >> 5, tc = t & 31;   // compute mapping
    const int qs = t >> 3, ts = t & 7;    // selection mapping

    if (t < 32) {
        int gr = FPSI[b * TD_S + qt * 32 + t];
        qrl[t] = gr; qqL[t] = XX[gr];
    }
    float sd[16]; int si[16];
#pragma unroll
    for (int r = 0; r < 16; ++r) { sd[r] = __builtin_inff(); si[r] = 0x7fffffff; }
    __syncthreads();

    for (int ct = 0; ct < 16; ++ct) {
        float acc[4][8];
#pragma unroll
        for (int qi = 0; qi < 4; ++qi)
#pragma unroll
            for (int cc = 0; cc < 8; ++cc) acc[qi][cc] = 0.0f;
        for (int kc = 0; kc < 8; ++kc) {
            __syncthreads();   // protects Xs reuse (prev compute / prev Dt reads)
            {
                int q = t >> 3, f4i = t & 7;
                float4 v = *(const float4*)&feat[(size_t)qrl[q] * 256 + kc * 32 + f4i * 4];
                Qs[(f4i * 4 + 0) * 36 + q] = v.x;
                Qs[(f4i * 4 + 1) * 36 + q] = v.y;
                Qs[(f4i * 4 + 2) * 36 + q] = v.z;
                Qs[(f4i * 4 + 3) * 36 + q] = v.w;
            }
#pragma unroll
            for (int p2 = 0; p2 < 8; ++p2) {
                int f4 = t + 256 * p2;
                int c = f4 >> 3, f4i = f4 & 7;
                float4 v = *(const float4*)&feat[(size_t)(cb + ct * 256 + c) * 256 + kc * 32 + f4i * 4];
                Xs[(f4i * 4 + 0) * 260 + c] = v.x;
                Xs[(f4i * 4 + 1) * 260 + c] = v.y;
                Xs[(f4i * 4 + 2) * 260 + c] = v.z;
                Xs[(f4i * 4 + 3) * 260 + c] = v.w;
            }
            __syncthreads();
#pragma unroll
            for (int kk = 0; kk < 32; ++kk) {
                float4 a  = *(float4*)&Qs[kk * 36 + tq * 4];
                float4 b0 = *(float4*)&Xs[kk * 260 + tc * 8];
                float4 b1 = *(float4*)&Xs[kk * 260 + tc * 8 + 4];
                float av[4]  = {a.x, a.y, a.z, a.w};
                float bv2[8] = {b0.x, b0.y, b0.z, b0.w, b1.x, b1.y, b1.z, b1.w};
#pragma unroll
                for (int qi = 0; qi < 4; ++qi)
#pragma unroll
                    for (int cc = 0; cc < 8; ++cc)
                        acc[qi][cc] = fmaf(av[qi], bv2[cc], acc[qi][cc]);
            }
        }
        __syncthreads();   // all Xs reads done; safe to overwrite as Dt
        float4 x0 = *(const float4*)&XX[cb + ct * 256 + tc * 8];
        float4 x1 = *(const float4*)&XX[cb + ct * 256 + tc * 8 + 4];
        float xv[8] = {x0.x, x0.y, x0.z, x0.w, x1.x, x1.y, x1.z, x1.w};
#pragma unroll
        for (int qi = 0; qi < 4; ++qi) {
            int q = tq * 4 + qi;
            float qq = qqL[q];
            float4 d0, d1;
            d0.x = (qq - 2.0f * acc[qi][0]) + xv[0];
            d0.y = (qq - 2.0f * acc[qi][1]) + xv[1];
            d0.z = (qq - 2.0f * acc[qi][2]) + xv[2];
            d0.w = (qq - 2.0f * acc[qi][3]) + xv[3];
            d1.x = (qq - 2.0f * acc[qi][4]) + xv[4];
            d1.y = (qq - 2.0f * acc[qi][5]) + xv[5];
            d1.z = (qq - 2.0f * acc[qi][6]) + xv[6];
            d1.w = (qq - 2.0f * acc[qi][7]) + xv[7];
            *(float4*)&Xs[q * 260 + tc * 8]     = d0;
            *(float4*)&Xs[q * 260 + tc * 8 + 4] = d1;
        }
        __syncthreads();
        // per-thread running top-16 over its stripe (ascending idx => ties keep low idx)
        for (int j = 0; j < 32; ++j) {
            int c = ts * 32 + j;
            float d = Xs[qs * 260 + c];
            int idx = ct * 256 + c;
            if (d < sd[15]) {
                sd[15] = d; si[15] = idx;
#pragma unroll
                for (int r = 15; r > 0; --r) {
                    if (sd[r] < sd[r - 1]) {
                        float td2 = sd[r]; sd[r] = sd[r - 1]; sd[r - 1] = td2;
                        int ti = si[r]; si[r] = si[r - 1]; si[r - 1] = ti;
                    }
                }
            }
        }
    }
    __syncthreads();
#pragma unroll
    for (int r = 0; r < 16; ++r) {
        int slot = ts * 16 + r;
        Xs[qs * 130 + slot] = sd[r];
        ((int*)Xs)[4160 + qs * 130 + slot] = si[r];
    }
    __syncthreads();
    if (t < 32) {
        int q = t;
#pragma unroll
        for (int r = 0; r < 16; ++r) { sd[r] = __builtin_inff(); si[r] = 0x7fffffff; }
        for (int m = 0; m < 128; ++m) {
            float d = Xs[q * 130 + m];
            int idx = ((int*)Xs)[4160 + q * 130 + m];
            if (d < sd[15] || (d == sd[15] && idx < si[15])) {
                sd[15] = d; si[15] = idx;
#pragma unroll
                for (int r = 15; r > 0; --r) {
                    bool sw = (sd[r] < sd[r - 1]) || (sd[r] == sd[r - 1] && si[r] < si[r - 1]);
                    if (sw) {
                        float td2 = sd[r]; sd[r] = sd[r - 1]; sd[r - 1] = td2;
                        int ti = si[r]; si[r] = si[r - 1]; si[r - 1] = ti;
                    }
                }
            }
        }
        int og = (b * TD_S + qt * 32 + q) * TD_K;
#pragma unroll
        for (int r = 0; r < 16; ++r) NN[og + r] = cb + si[r];
    }
}

__global__ __launch_bounds__(256)
void td_maxpool(const unsigned short* __restrict__ H, const int* __restrict__ NN,
                const float* __restrict__ SS, float* __restrict__ outF) {
    __shared__ int nbr[16];
    const int g = blockIdx.x, t = threadIdx.x;
    if (t < 16) nbr[t] = NN[g * 16 + t];
    __syncthreads();
    float sc0 = SS[2 * t], sc1 = SS[2 * t + 1];
    float sh0 = SS[512 + 2 * t], sh1 = SS[512 + 2 * t + 1];
    float m0 = 0.0f, m1 = 0.0f;   // relu floor: max_k relu(v) = max(0, max_k v)
#pragma unroll
    for (int k = 0; k < 16; ++k) {
        int row = nbr[k];
        unsigned u = ((const unsigned*)(H + (size_t)row * 512))[t];
        float lo = __uint_as_float(u << 16);
        float hi = __uint_as_float(u & 0xffff0000u);
        m0 = fmaxf(m0, fmaf(sc0, lo, sh0));
        m1 = fmaxf(m1, fmaf(sc1, hi, sh1));
    }
    float2 o; o.x = m0; o.y = m1;
    *(float2*)&outF[(size_t)g * 512 + 2 * t] = o;
}

extern "C" void kernel_launch(void* const* d_in, const int* in_sizes, int n_in,
                              void* d_out, int out_size, void* d_ws, size_t ws_size,
                              hipStream_t stream) {
    const float* feat  = (const float*)d_in[0];
    const float* pos   = (const float*)d_in[1];
    // d_in[2] = batch (int32): unused, value is row/P by construction
    const float* W     = (const float*)d_in[3];
    const float* bias  = (const float*)d_in[4];
    const float* gamma = (const float*)d_in[5];
    const float* beta  = (const float*)d_in[6];

    char* ws = (char*)d_ws;
    unsigned short* H = (unsigned short*)ws;            // 67,108,864 B  (bf16 h)
    float* XX  = (float*)(ws + 67108864);               //    262,144 B
    int*   FPSI= (int*)  (ws + 67371008);               //     65,536 B
    int*   NN  = (int*)  (ws + 67436544);               //  1,048,576 B
    float* P1  = (float*)(ws + 68485120);               //    262,144 B used
    float* P2  = (float*)(ws + 69533696);               //    262,144 B used
    float* SS  = (float*)(ws + 70582272);               //      4,096 B

    float* outF = (float*)d_out;
    float* outP = outF + (size_t)TD_B * TD_S * TD_OUTF;   // 8,388,608
    float* outB = outP + (size_t)TD_B * TD_S * 3;         // +49,152

    td_fused  <<<2064, 512, 0, stream>>>(feat, pos, W, bias, H, XX, FPSI, outP, outB);
    td_stats  <<<128, 256, 0, stream>>>(H, P1, P2);
    td_bnfin  <<<1, 512, 0, stream>>>(P1, P2, gamma, beta, SS);
    td_knn    <<<512, 256, 0, stream>>>(feat, XX, FPSI, NN);
    td_maxpool<<<TD_B * TD_S, 256, 0, stream>>>(H, NN, SS, outF);
}

// Round 3
// 1427.626 us; speedup vs baseline: 1.7029x; 1.2111x over previous
//
#include <hip/hip_runtime.h>
#include <cstddef>

// TransitionDown: B=16 clouds, P=4096 pts, S=1024 fps samples, K=16 knn,
// IN_F=256, OUT_F=512.
// Pipeline:
//   L1 fused: blocks[0,16)   FPS per cloud (np-bitwise fp32, no FMA)
//             blocks[16,1040) MLP GEMM fp32 -> h bf16 (hidden under FPS)
//             blocks[1040,2064) xx[i] = ||features_i||^2
//   L2: BN partial sums over h   L3: BN finalize -> scale/shift
//   L4: KNN via fp16-split MFMA (S = QhXh + QhXl + QlXh), per-segment top-16
//   L5: exact 4-way merge of segment partials -> NN
//   L6: gather + BN + ReLU + max over K

#define TD_B   16
#define TD_P   4096
#define TD_S   1024
#define TD_K   16
#define TD_INF 256
#define TD_OUTF 512

typedef __attribute__((ext_vector_type(8))) _Float16 half8;
typedef __attribute__((ext_vector_type(4))) float    f32x4;

__device__ __forceinline__ unsigned short f2bf(float x) {
    unsigned u = __float_as_uint(x);
    unsigned r = (u + 0x7fffu + ((u >> 16) & 1u)) >> 16;   // RNE
    return (unsigned short)r;
}

struct FpsSm {
    float sx[TD_P]; float sy[TD_P]; float sz[TD_P];
    int   sel[TD_S];
    double kw[2][8];      // parity-double-buffered per-wave argmax keys
};
struct GemmSm {
    float As[16 * 260];   // [k][m]
    float Bs[16 * 128];   // [k][n]
};
union SmU { FpsSm f; GemmSm g; };

__global__ __launch_bounds__(512)
void td_fused(const float* __restrict__ feat, const float* __restrict__ pos,
              const float* __restrict__ W, const float* __restrict__ bias,
              unsigned short* __restrict__ H, float* __restrict__ XX,
              int* __restrict__ FPSI, float* __restrict__ outP,
              float* __restrict__ outB) {
    __shared__ SmU sm;
    const int bx = blockIdx.x;
    const int t  = threadIdx.x;

    if (bx < 16) {
        // ---------------- FPS: one block per cloud ---------------------------
        // key = double with hi32 = fp32 bits of min_d, lo32 = ~p
        // (max => largest d, tie -> lowest p). np-bitwise math, no FMA.
        __builtin_amdgcn_s_setprio(2);
        const int b = bx;
        const int w = t >> 6;
        float px[8], py[8], pz[8], md[8];
        int ni[8];
#pragma unroll
        for (int j = 0; j < 8; ++j) {
            int p = j * 512 + t;
            const float* pp = pos + (size_t)(b * TD_P + p) * 3;
            float x = pp[0], y = pp[1], z = pp[2];
            px[j] = x; py[j] = y; pz[j] = z;
            sm.f.sx[p] = x; sm.f.sy[p] = y; sm.f.sz[p] = z;
            md[j] = __builtin_inff();
            ni[j] = ~p;
        }
        if (t == 0) sm.f.sel[0] = 0;
        __syncthreads();
        float lx = sm.f.sx[0], ly = sm.f.sy[0], lz = sm.f.sz[0];
        for (int s = 0; s < TD_S - 1; ++s) {
            double kmax = 0.0;
#pragma unroll
            for (int j = 0; j < 8; ++j) {
                float dx = __fsub_rn(px[j], lx);
                float dy = __fsub_rn(py[j], ly);
                float dz = __fsub_rn(pz[j], lz);
                float d  = __fadd_rn(__fadd_rn(__fmul_rn(dx, dx), __fmul_rn(dy, dy)),
                                     __fmul_rn(dz, dz));
                float m  = fminf(md[j], d);
                md[j] = m;
                double k = __hiloint2double(__float_as_int(m), ni[j]);
                kmax = fmax(kmax, k);
            }
#pragma unroll
            for (int off = 32; off > 0; off >>= 1)
                kmax = fmax(kmax, __shfl_xor(kmax, off, 64));
            const int par = s & 1;
            if ((t & 63) == 0) sm.f.kw[par][w] = kmax;
            __syncthreads();
            double gk = sm.f.kw[par][0];
#pragma unroll
            for (int i = 1; i < 8; ++i) gk = fmax(gk, sm.f.kw[par][i]);
            unsigned idx = ~(unsigned)(unsigned long long)__double_as_longlong(gk);
            if (t == 0) sm.f.sel[s + 1] = (int)idx;
            lx = sm.f.sx[idx]; ly = sm.f.sy[idx]; lz = sm.f.sz[idx];
        }
        __syncthreads();
        for (int s = t; s < TD_S; s += 512) {
            int li = sm.f.sel[s];
            int og = b * TD_S + s;
            outP[og * 3 + 0] = sm.f.sx[li];
            outP[og * 3 + 1] = sm.f.sy[li];
            outP[og * 3 + 2] = sm.f.sz[li];
            outB[og] = (float)b;
            FPSI[og] = b * TD_P + li;   // global row index
        }
    } else if (bx < 16 + 1024) {
        // ---------------- MLP GEMM: 256x128 tile, 512 thr, 8x8 micro ---------
        const int gb = bx - 16;
        const int mb = gb >> 2, nb = gb & 3;
        const int tm = t >> 4, tn = t & 15;
        float acc[8][8];
#pragma unroll
        for (int i = 0; i < 8; ++i)
#pragma unroll
            for (int j = 0; j < 8; ++j) acc[i][j] = 0.0f;
        float* As = sm.g.As;
        float* Bs = sm.g.Bs;
        for (int kc = 0; kc < 16; ++kc) {
#pragma unroll
            for (int p2 = 0; p2 < 2; ++p2) {
                int f4 = t + 512 * p2;
                int r = f4 >> 2, c4 = f4 & 3;
                float4 v = *(const float4*)&feat[(size_t)(mb * 256 + r) * 256 + kc * 16 + c4 * 4];
                As[(c4 * 4 + 0) * 260 + r] = v.x;
                As[(c4 * 4 + 1) * 260 + r] = v.y;
                As[(c4 * 4 + 2) * 260 + r] = v.z;
                As[(c4 * 4 + 3) * 260 + r] = v.w;
            }
            {
                int kk = t >> 5, n4 = t & 31;
                float4 v = *(const float4*)&W[(size_t)(kc * 16 + kk) * 512 + nb * 128 + n4 * 4];
                *(float4*)&Bs[kk * 128 + n4 * 4] = v;
            }
            __syncthreads();
#pragma unroll
            for (int kk = 0; kk < 16; ++kk) {
                float4 a0 = *(float4*)&As[kk * 260 + tm * 8];
                float4 a1 = *(float4*)&As[kk * 260 + tm * 8 + 4];
                float4 b0 = *(float4*)&Bs[kk * 128 + tn * 8];
                float4 b1 = *(float4*)&Bs[kk * 128 + tn * 8 + 4];
                float av[8] = {a0.x, a0.y, a0.z, a0.w, a1.x, a1.y, a1.z, a1.w};
                float bv2[8] = {b0.x, b0.y, b0.z, b0.w, b1.x, b1.y, b1.z, b1.w};
#pragma unroll
                for (int i = 0; i < 8; ++i)
#pragma unroll
                    for (int j = 0; j < 8; ++j)
                        acc[i][j] = fmaf(av[i], bv2[j], acc[i][j]);
            }
            __syncthreads();
        }
        float4 bb0 = *(const float4*)&bias[nb * 128 + tn * 8];
        float4 bb1 = *(const float4*)&bias[nb * 128 + tn * 8 + 4];
        float bsv[8] = {bb0.x, bb0.y, bb0.z, bb0.w, bb1.x, bb1.y, bb1.z, bb1.w};
#pragma unroll
        for (int i = 0; i < 8; ++i) {
            int row = mb * 256 + tm * 8 + i;
            uint4 pk;
            pk.x = (unsigned)f2bf(acc[i][0] + bsv[0]) | ((unsigned)f2bf(acc[i][1] + bsv[1]) << 16);
            pk.y = (unsigned)f2bf(acc[i][2] + bsv[2]) | ((unsigned)f2bf(acc[i][3] + bsv[3]) << 16);
            pk.z = (unsigned)f2bf(acc[i][4] + bsv[4]) | ((unsigned)f2bf(acc[i][5] + bsv[5]) << 16);
            pk.w = (unsigned)f2bf(acc[i][6] + bsv[6]) | ((unsigned)f2bf(acc[i][7] + bsv[7]) << 16);
            *(uint4*)&H[(size_t)row * 512 + nb * 128 + tn * 8] = pk;
        }
    } else {
        // ---------------- xx[i] = ||features_i||^2 ---------------------------
        const int xb = bx - 1040;
        const int w = t >> 6, lane = t & 63;
#pragma unroll
        for (int it = 0; it < 8; ++it) {
            int r = xb * 64 + w * 8 + it;
            float4 v = *(const float4*)&feat[(size_t)r * 256 + lane * 4];
            float s = v.x * v.x + v.y * v.y + v.z * v.z + v.w * v.w;
#pragma unroll
            for (int off = 32; off > 0; off >>= 1) s += __shfl_down(s, off, 64);
            if (lane == 0) XX[r] = s;
        }
    }
}

__global__ __launch_bounds__(256)
void td_stats(const unsigned short* __restrict__ H, float* __restrict__ P1,
              float* __restrict__ P2) {
    const int rb = blockIdx.x, t = threadIdx.x;   // 128 blocks x 512 rows
    float s1a = 0, s2a = 0, s1b = 0, s2b = 0;
    for (int r = 0; r < 512; ++r) {
        const unsigned* hp = (const unsigned*)(H + (size_t)(rb * 512 + r) * 512);
        unsigned u = hp[t];
        float lo = __uint_as_float(u << 16);
        float hi = __uint_as_float(u & 0xffff0000u);
        s1a += lo; s2a = fmaf(lo, lo, s2a);
        s1b += hi; s2b = fmaf(hi, hi, s2b);
    }
    P1[rb * 512 + 2 * t] = s1a; P1[rb * 512 + 2 * t + 1] = s1b;
    P2[rb * 512 + 2 * t] = s2a; P2[rb * 512 + 2 * t + 1] = s2b;
}

__global__ __launch_bounds__(512)
void td_bnfin(const float* __restrict__ P1, const float* __restrict__ P2,
              const float* __restrict__ gamma, const float* __restrict__ beta,
              float* __restrict__ SS) {
    const int ch = threadIdx.x;
    float s1 = 0, s2 = 0;
    for (int rb = 0; rb < 128; ++rb) { s1 += P1[rb * 512 + ch]; s2 += P2[rb * 512 + ch]; }
    const float invN = 1.0f / 65536.0f;
    float mu  = s1 * invN;
    float var = s2 * invN - mu * mu;
    float sc  = gamma[ch] * (1.0f / sqrtf(var + 1e-5f));
    float sh  = beta[ch] - mu * sc;
    SS[ch] = sc; SS[512 + ch] = sh;
}

// ---------------------------------------------------------------------------
// KNN via MFMA, fp16 split (hi/lo), 3-pass: S = QhXh + QhXl + QlXh.
// Grid 256 = 16 clouds x 4 q-groups(256q) x 4 candidate segments(1024c).
// bx&15 = cloud  => all 16 blocks of a cloud land on XCD cloud%8 (i%8 rr).
// Block 256 thr = 4 waves; wave owns 64 q (4 subtiles of 16), Q frags in
// 256 VGPRs. Candidates staged 32/chunk in LDS (hi+lo), read by all 4 waves.
// Per-thread exact top-16 over its segment, sorted (d asc, idx asc).
// ---------------------------------------------------------------------------
__global__ __launch_bounds__(256, 1)
void td_knn2(const float* __restrict__ feat, const float* __restrict__ XX,
             const int* __restrict__ FPSI, float* __restrict__ PD,
             int* __restrict__ PI) {
    __shared__ union {
        _Float16 x[2][32][264];   // [hi/lo][c][k], row pad 8 halfs (stride%32w==4)
        float    dt[256][33];     // aliased after MFMA: d values [q_local][c_local]
    } sm;
    __shared__ float QQs[256];
    __shared__ int   QR[256];

    const int bx = blockIdx.x, t = threadIdx.x;
    const int b = bx & 15, r2 = bx >> 4;
    const int qq4 = r2 >> 2, seg = r2 & 3;
    const int cb = b * TD_P;
    const int segbase = cb + seg * 1024;

    {   // query rows + norms
        int gr = FPSI[b * TD_S + qq4 * 256 + t];
        QR[t] = gr; QQs[t] = XX[gr];
    }
    __syncthreads();

    const int w = t >> 6, lane = t & 63;
    const int m = lane & 15, quad = lane >> 4;

    // ---- Q fragments into registers (A-op: lane holds Q[m][quad*8+j]) ------
    half8 qh[4][8], ql[4][8];
#pragma unroll
    for (int qs = 0; qs < 4; ++qs) {
        const float* qp = feat + (size_t)QR[w * 64 + qs * 16 + m] * 256;
#pragma unroll
        for (int ks = 0; ks < 8; ++ks) {
            float4 f0 = *(const float4*)(qp + ks * 32 + quad * 8);
            float4 f1 = *(const float4*)(qp + ks * 32 + quad * 8 + 4);
            float fv[8] = {f0.x, f0.y, f0.z, f0.w, f1.x, f1.y, f1.z, f1.w};
            half8 h, l;
#pragma unroll
            for (int j = 0; j < 8; ++j) {
                _Float16 hv = (_Float16)fv[j];
                h[j] = hv;
                l[j] = (_Float16)(fv[j] - (float)hv);
            }
            qh[qs][ks] = h; ql[qs][ks] = l;
        }
    }

    float sd[16]; int si[16];
#pragma unroll
    for (int r = 0; r < 16; ++r) { sd[r] = __builtin_inff(); si[r] = 0x7fffffff; }

    const int xrow = t >> 3, part = t & 7;   // staging mapping

    for (int ct = 0; ct < 32; ++ct) {
        __syncthreads();   // prev selection done reading dt (aliases x)
        // ---- stage 32 candidates x 256 k, fp32 -> fp16 hi/lo ---------------
        {
            const float* xp = feat + (size_t)(segbase + ct * 32 + xrow) * 256 + part * 32;
#pragma unroll
            for (int s2 = 0; s2 < 4; ++s2) {
                float4 f0 = *(const float4*)(xp + s2 * 8);
                float4 f1 = *(const float4*)(xp + s2 * 8 + 4);
                float fv[8] = {f0.x, f0.y, f0.z, f0.w, f1.x, f1.y, f1.z, f1.w};
                half8 h, l;
#pragma unroll
                for (int j = 0; j < 8; ++j) {
                    _Float16 hv = (_Float16)fv[j];
                    h[j] = hv;
                    l[j] = (_Float16)(fv[j] - (float)hv);
                }
                *(half8*)&sm.x[0][xrow][part * 32 + s2 * 8] = h;
                *(half8*)&sm.x[1][xrow][part * 32 + s2 * 8] = l;
            }
        }
        __syncthreads();
        // ---- MFMA: acc[qs][cs] over K=256 ---------------------------------
        f32x4 acc[4][2];
#pragma unroll
        for (int qs = 0; qs < 4; ++qs) { acc[qs][0] = (f32x4)0.0f; acc[qs][1] = (f32x4)0.0f; }
#pragma unroll
        for (int ks = 0; ks < 8; ++ks) {
            half8 xh0 = *(half8*)&sm.x[0][m][ks * 32 + quad * 8];
            half8 xl0 = *(half8*)&sm.x[1][m][ks * 32 + quad * 8];
            half8 xh1 = *(half8*)&sm.x[0][16 + m][ks * 32 + quad * 8];
            half8 xl1 = *(half8*)&sm.x[1][16 + m][ks * 32 + quad * 8];
#pragma unroll
            for (int qs = 0; qs < 4; ++qs) {
                acc[qs][0] = __builtin_amdgcn_mfma_f32_16x16x32_f16(ql[qs][ks], xh0, acc[qs][0], 0, 0, 0);
                acc[qs][0] = __builtin_amdgcn_mfma_f32_16x16x32_f16(qh[qs][ks], xl0, acc[qs][0], 0, 0, 0);
                acc[qs][0] = __builtin_amdgcn_mfma_f32_16x16x32_f16(qh[qs][ks], xh0, acc[qs][0], 0, 0, 0);
                acc[qs][1] = __builtin_amdgcn_mfma_f32_16x16x32_f16(ql[qs][ks], xh1, acc[qs][1], 0, 0, 0);
                acc[qs][1] = __builtin_amdgcn_mfma_f32_16x16x32_f16(qh[qs][ks], xl1, acc[qs][1], 0, 0, 0);
                acc[qs][1] = __builtin_amdgcn_mfma_f32_16x16x32_f16(qh[qs][ks], xh1, acc[qs][1], 0, 0, 0);
            }
        }
        __syncthreads();   // all waves done reading x; safe to alias as dt
        // ---- epilogue: d = (qq - 2S) + xx, dump to dt ----------------------
        {
            float xx0 = XX[segbase + ct * 32 + m];
            float xx1 = XX[segbase + ct * 32 + 16 + m];
#pragma unroll
            for (int qs = 0; qs < 4; ++qs) {
                int qb = w * 64 + qs * 16 + quad * 4;
#pragma unroll
                for (int reg = 0; reg < 4; ++reg) {
                    float qq = QQs[qb + reg];
                    sm.dt[qb + reg][m]      = (qq - 2.0f * acc[qs][0][reg]) + xx0;
                    sm.dt[qb + reg][16 + m] = (qq - 2.0f * acc[qs][1][reg]) + xx1;
                }
            }
        }
        __syncthreads();
        // ---- selection: thread t owns query t, scans 32 candidates ---------
        const int ibase = segbase + ct * 32;
        for (int j = 0; j < 32; ++j) {
            float d = sm.dt[t][j];
            if (d < sd[15]) {
                sd[15] = d; si[15] = ibase + j;   // ascending idx => strict < ok
#pragma unroll
                for (int r = 15; r > 0; --r) {
                    if (sd[r] < sd[r - 1]) {
                        float td2 = sd[r]; sd[r] = sd[r - 1]; sd[r - 1] = td2;
                        int ti = si[r]; si[r] = si[r - 1]; si[r - 1] = ti;
                    }
                }
            }
        }
    }
    // ---- write sorted per-segment partial top-16 ---------------------------
    size_t o = ((size_t)(b * TD_S + qq4 * 256 + t)) * 64 + seg * 16;
#pragma unroll
    for (int r = 0; r < 16; ++r) { PD[o + r] = sd[r]; PI[o + r] = si[r]; }
}

// Exact 4-way merge of sorted segment partials -> final top-16 per query.
__global__ __launch_bounds__(64)
void td_merge(const float* __restrict__ PD, const int* __restrict__ PI,
              int* __restrict__ NN) {
    __shared__ float ld_[64][65];
    __shared__ int   li_[64][65];
    const int bx = blockIdx.x, t = threadIdx.x;
    for (int j = 0; j < 64; ++j) {
        ld_[j][t] = PD[(size_t)bx * 4096 + j * 64 + t];
        li_[j][t] = PI[(size_t)bx * 4096 + j * 64 + t];
    }
    __syncthreads();
    int p[4] = {0, 0, 0, 0};
    int og = (bx * 64 + t) * TD_K;
    for (int r = 0; r < 16; ++r) {
        float bd = __builtin_inff(); int bi = 0x7fffffff; int bs = 0;
#pragma unroll
        for (int s = 0; s < 4; ++s) {
            if (p[s] < 16) {
                float d = ld_[t][s * 16 + p[s]];
                int   i = li_[t][s * 16 + p[s]];
                if (d < bd || (d == bd && i < bi)) { bd = d; bi = i; bs = s; }
            }
        }
        p[bs]++;
        NN[og + r] = bi;
    }
}

__global__ __launch_bounds__(256)
void td_maxpool(const unsigned short* __restrict__ H, const int* __restrict__ NN,
                const float* __restrict__ SS, float* __restrict__ outF) {
    __shared__ int nbr[16];
    const int g = blockIdx.x, t = threadIdx.x;
    if (t < 16) nbr[t] = NN[g * 16 + t];
    __syncthreads();
    float sc0 = SS[2 * t], sc1 = SS[2 * t + 1];
    float sh0 = SS[512 + 2 * t], sh1 = SS[512 + 2 * t + 1];
    float m0 = 0.0f, m1 = 0.0f;   // relu floor: max_k relu(v) = max(0, max_k v)
#pragma unroll
    for (int k = 0; k < 16; ++k) {
        int row = nbr[k];
        unsigned u = ((const unsigned*)(H + (size_t)row * 512))[t];
        float lo = __uint_as_float(u << 16);
        float hi = __uint_as_float(u & 0xffff0000u);
        m0 = fmaxf(m0, fmaf(sc0, lo, sh0));
        m1 = fmaxf(m1, fmaf(sc1, hi, sh1));
    }
    float2 o; o.x = m0; o.y = m1;
    *(float2*)&outF[(size_t)g * 512 + 2 * t] = o;
}

extern "C" void kernel_launch(void* const* d_in, const int* in_sizes, int n_in,
                              void* d_out, int out_size, void* d_ws, size_t ws_size,
                              hipStream_t stream) {
    const float* feat  = (const float*)d_in[0];
    const float* pos   = (const float*)d_in[1];
    // d_in[2] = batch (int32): unused, value is row/P by construction
    const float* W     = (const float*)d_in[3];
    const float* bias  = (const float*)d_in[4];
    const float* gamma = (const float*)d_in[5];
    const float* beta  = (const float*)d_in[6];

    char* ws = (char*)d_ws;
    unsigned short* H = (unsigned short*)ws;            // 67,108,864 B (bf16 h)
    float* XX  = (float*)(ws + 67108864);               //    262,144 B
    int*   FPSI= (int*)  (ws + 67371008);               //     65,536 B
    int*   NN  = (int*)  (ws + 67436544);               //  1,048,576 B
    float* P1  = (float*)(ws + 68485120);               //    262,144 B used
    float* P2  = (float*)(ws + 69533696);               //    262,144 B used
    float* SS  = (float*)(ws + 70582272);               //      4,096 B
    float* PD  = (float*)(ws + 70586368);               //  4,194,304 B
    int*   PI  = (int*)  (ws + 74780672);               //  4,194,304 B

    float* outF = (float*)d_out;
    float* outP = outF + (size_t)TD_B * TD_S * TD_OUTF;   // 8,388,608
    float* outB = outP + (size_t)TD_B * TD_S * 3;         // +49,152

    td_fused  <<<2064, 512, 0, stream>>>(feat, pos, W, bias, H, XX, FPSI, outP, outB);
    td_stats  <<<128, 256, 0, stream>>>(H, P1, P2);
    td_bnfin  <<<1, 512, 0, stream>>>(P1, P2, gamma, beta, SS);
    td_knn2   <<<256, 256, 0, stream>>>(feat, XX, FPSI, PD, PI);
    td_merge  <<<256, 64, 0, stream>>>(PD, PI, NN);
    td_maxpool<<<TD_B * TD_S, 256, 0, stream>>>(H, NN, SS, outF);
}

// Round 4
// 1147.663 us; speedup vs baseline: 2.1184x; 1.2439x over previous
//
#include <hip/hip_runtime.h>
#include <cstddef>

// TransitionDown: B=16 clouds, P=4096 pts, S=1024 fps samples, K=16 knn,
// IN_F=256, OUT_F=512.
// Pipeline:
//   L1 fused: blocks[0,16)   FPS per cloud (np-bitwise fp32, no FMA),
//                            DPP wave-argmax, 1 barrier/step
//             blocks[16,1040) MLP GEMM fp32 -> h bf16 (hidden under FPS)
//             blocks[1040,2064) xx[i] = ||features_i||^2
//   L2: BN partial sums over h   L3: BN finalize -> scale/shift
//   L4: KNN via fp16-split MFMA (S = QhXh + QhXl + QlXh), per-segment top-16
//   L5: exact 4-way merge of segment partials -> NN
//   L6: gather + BN + ReLU + max over K

#define TD_B   16
#define TD_P   4096
#define TD_S   1024
#define TD_K   16
#define TD_INF 256
#define TD_OUTF 512

typedef __attribute__((ext_vector_type(8))) _Float16 half8;
typedef __attribute__((ext_vector_type(4))) float    f32x4;

__device__ __forceinline__ unsigned short f2bf(float x) {
    unsigned u = __float_as_uint(x);
    unsigned r = (u + 0x7fffu + ((u >> 16) & 1u)) >> 16;   // RNE
    return (unsigned short)r;
}

// Wave64 max-reduce on u32 via DPP (VALU pipe, no LDS). Result valid in lane 63.
__device__ __forceinline__ unsigned wred_umax(unsigned x) {
    unsigned y;
    y = (unsigned)__builtin_amdgcn_update_dpp(0, (int)x, 0x111, 0xf, 0xf, true);  x = x > y ? x : y; // row_shr:1
    y = (unsigned)__builtin_amdgcn_update_dpp(0, (int)x, 0x112, 0xf, 0xf, true);  x = x > y ? x : y; // row_shr:2
    y = (unsigned)__builtin_amdgcn_update_dpp(0, (int)x, 0x114, 0xf, 0xf, true);  x = x > y ? x : y; // row_shr:4
    y = (unsigned)__builtin_amdgcn_update_dpp(0, (int)x, 0x118, 0xf, 0xf, true);  x = x > y ? x : y; // row_shr:8
    y = (unsigned)__builtin_amdgcn_update_dpp(0, (int)x, 0x142, 0xf, 0xf, false); x = x > y ? x : y; // row_bcast:15
    y = (unsigned)__builtin_amdgcn_update_dpp(0, (int)x, 0x143, 0xf, 0xf, false); x = x > y ? x : y; // row_bcast:31
    return x;
}

struct FpsSm {
    float4 p4[TD_P];      // 64 KB: (x,y,z,-) per point, single b128 winner read
    int    sel[TD_S];
    uint2  kw[2][8];      // parity-double-buffered per-wave (d_bits, ~p)
};
struct GemmSm {
    float As[16 * 260];   // [k][m]
    float Bs[16 * 128];   // [k][n]
};
union SmU { FpsSm f; GemmSm g; };

__device__ __forceinline__ double kpack(uint2 u) {
    return __hiloint2double((int)u.x, (int)u.y);
}

__global__ __launch_bounds__(512)
void td_fused(const float* __restrict__ feat, const float* __restrict__ pos,
              const float* __restrict__ W, const float* __restrict__ bias,
              unsigned short* __restrict__ H, float* __restrict__ XX,
              int* __restrict__ FPSI, float* __restrict__ outP,
              float* __restrict__ outB) {
    __shared__ SmU sm;
    const int bx = blockIdx.x;
    const int t  = threadIdx.x;

    if (bx < 16) {
        // ---------------- FPS: one block per cloud ---------------------------
        // In-lane: packed f64 key (hi=fp32 bits of min_d, lo=~p), depth-3 tree.
        // Cross-lane: u32 DPP max on d-bits (monotone for d>=0), readlane 63,
        // then masked DPP max on ~p for the tie-break (lowest p wins).
        // Cross-wave: 8 uint2 in LDS, broadcast merge as f64 keys.
        __builtin_amdgcn_s_setprio(2);
        const int b = bx;
        const int w = t >> 6;
        float px[8], py[8], pz[8], md[8];
        int ni[8];
#pragma unroll
        for (int j = 0; j < 8; ++j) {
            int p = j * 512 + t;
            const float* pp = pos + (size_t)(b * TD_P + p) * 3;
            float x = pp[0], y = pp[1], z = pp[2];
            px[j] = x; py[j] = y; pz[j] = z;
            sm.f.p4[p] = make_float4(x, y, z, 0.0f);
            md[j] = __builtin_inff();
            ni[j] = ~p;
        }
        if (t == 0) sm.f.sel[0] = 0;
        __syncthreads();
        float lx = sm.f.p4[0].x, ly = sm.f.p4[0].y, lz = sm.f.p4[0].z;
        for (int s = 0; s < TD_S - 1; ++s) {
            double k[8];
#pragma unroll
            for (int j = 0; j < 8; ++j) {
                // exact np order: sub, sq, sq, sq, add, add, min (no contraction)
                float dx = __fsub_rn(px[j], lx);
                float dy = __fsub_rn(py[j], ly);
                float dz = __fsub_rn(pz[j], lz);
                float d  = __fadd_rn(__fadd_rn(__fmul_rn(dx, dx), __fmul_rn(dy, dy)),
                                     __fmul_rn(dz, dz));
                float m  = fminf(md[j], d);
                md[j] = m;
                k[j] = __hiloint2double(__float_as_int(m), ni[j]);
            }
            double k01 = fmax(k[0], k[1]), k23 = fmax(k[2], k[3]);
            double k45 = fmax(k[4], k[5]), k67 = fmax(k[6], k[7]);
            double kk  = fmax(fmax(k01, k23), fmax(k45, k67));
            unsigned dw = (unsigned)__double2hiint(kk);
            unsigned nw = (unsigned)__double2loint(kk);
            unsigned rd   = wred_umax(dw);
            unsigned smax = (unsigned)__builtin_amdgcn_readlane((int)rd, 63);
            unsigned cand = (dw == smax) ? nw : 0u;
            unsigned rn   = wred_umax(cand);
            unsigned snp  = (unsigned)__builtin_amdgcn_readlane((int)rn, 63);
            const int par = s & 1;
            if ((t & 63) == 0) sm.f.kw[par][w] = make_uint2(smax, snp);
            __syncthreads();
            const uint2* kwp = sm.f.kw[par];
            double g01 = fmax(kpack(kwp[0]), kpack(kwp[1]));
            double g23 = fmax(kpack(kwp[2]), kpack(kwp[3]));
            double g45 = fmax(kpack(kwp[4]), kpack(kwp[5]));
            double g67 = fmax(kpack(kwp[6]), kpack(kwp[7]));
            double gk  = fmax(fmax(g01, g23), fmax(g45, g67));
            unsigned idx = ~(unsigned)__double2loint(gk);
            if (t == 0) sm.f.sel[s + 1] = (int)idx;
            float4 wp = sm.f.p4[idx];
            lx = wp.x; ly = wp.y; lz = wp.z;
        }
        __syncthreads();
        for (int s = t; s < TD_S; s += 512) {
            int li = sm.f.sel[s];
            int og = b * TD_S + s;
            float4 wp = sm.f.p4[li];
            outP[og * 3 + 0] = wp.x;
            outP[og * 3 + 1] = wp.y;
            outP[og * 3 + 2] = wp.z;
            outB[og] = (float)b;
            FPSI[og] = b * TD_P + li;   // global row index
        }
    } else if (bx < 16 + 1024) {
        // ---------------- MLP GEMM: 256x128 tile, 512 thr, 8x8 micro ---------
        const int gb = bx - 16;
        const int mb = gb >> 2, nb = gb & 3;
        const int tm = t >> 4, tn = t & 15;
        float acc[8][8];
#pragma unroll
        for (int i = 0; i < 8; ++i)
#pragma unroll
            for (int j = 0; j < 8; ++j) acc[i][j] = 0.0f;
        float* As = sm.g.As;
        float* Bs = sm.g.Bs;
        for (int kc = 0; kc < 16; ++kc) {
#pragma unroll
            for (int p2 = 0; p2 < 2; ++p2) {
                int f4 = t + 512 * p2;
                int r = f4 >> 2, c4 = f4 & 3;
                float4 v = *(const float4*)&feat[(size_t)(mb * 256 + r) * 256 + kc * 16 + c4 * 4];
                As[(c4 * 4 + 0) * 260 + r] = v.x;
                As[(c4 * 4 + 1) * 260 + r] = v.y;
                As[(c4 * 4 + 2) * 260 + r] = v.z;
                As[(c4 * 4 + 3) * 260 + r] = v.w;
            }
            {
                int kk = t >> 5, n4 = t & 31;
                float4 v = *(const float4*)&W[(size_t)(kc * 16 + kk) * 512 + nb * 128 + n4 * 4];
                *(float4*)&Bs[kk * 128 + n4 * 4] = v;
            }
            __syncthreads();
#pragma unroll
            for (int kk = 0; kk < 16; ++kk) {
                float4 a0 = *(float4*)&As[kk * 260 + tm * 8];
                float4 a1 = *(float4*)&As[kk * 260 + tm * 8 + 4];
                float4 b0 = *(float4*)&Bs[kk * 128 + tn * 8];
                float4 b1 = *(float4*)&Bs[kk * 128 + tn * 8 + 4];
                float av[8] = {a0.x, a0.y, a0.z, a0.w, a1.x, a1.y, a1.z, a1.w};
                float bv2[8] = {b0.x, b0.y, b0.z, b0.w, b1.x, b1.y, b1.z, b1.w};
#pragma unroll
                for (int i = 0; i < 8; ++i)
#pragma unroll
                    for (int j = 0; j < 8; ++j)
                        acc[i][j] = fmaf(av[i], bv2[j], acc[i][j]);
            }
            __syncthreads();
        }
        float4 bb0 = *(const float4*)&bias[nb * 128 + tn * 8];
        float4 bb1 = *(const float4*)&bias[nb * 128 + tn * 8 + 4];
        float bsv[8] = {bb0.x, bb0.y, bb0.z, bb0.w, bb1.x, bb1.y, bb1.z, bb1.w};
#pragma unroll
        for (int i = 0; i < 8; ++i) {
            int row = mb * 256 + tm * 8 + i;
            uint4 pk;
            pk.x = (unsigned)f2bf(acc[i][0] + bsv[0]) | ((unsigned)f2bf(acc[i][1] + bsv[1]) << 16);
            pk.y = (unsigned)f2bf(acc[i][2] + bsv[2]) | ((unsigned)f2bf(acc[i][3] + bsv[3]) << 16);
            pk.z = (unsigned)f2bf(acc[i][4] + bsv[4]) | ((unsigned)f2bf(acc[i][5] + bsv[5]) << 16);
            pk.w = (unsigned)f2bf(acc[i][6] + bsv[6]) | ((unsigned)f2bf(acc[i][7] + bsv[7]) << 16);
            *(uint4*)&H[(size_t)row * 512 + nb * 128 + tn * 8] = pk;
        }
    } else {
        // ---------------- xx[i] = ||features_i||^2 ---------------------------
        const int xb = bx - 1040;
        const int w = t >> 6, lane = t & 63;
#pragma unroll
        for (int it = 0; it < 8; ++it) {
            int r = xb * 64 + w * 8 + it;
            float4 v = *(const float4*)&feat[(size_t)r * 256 + lane * 4];
            float s = v.x * v.x + v.y * v.y + v.z * v.z + v.w * v.w;
#pragma unroll
            for (int off = 32; off > 0; off >>= 1) s += __shfl_down(s, off, 64);
            if (lane == 0) XX[r] = s;
        }
    }
}

__global__ __launch_bounds__(256)
void td_stats(const unsigned short* __restrict__ H, float* __restrict__ P1,
              float* __restrict__ P2) {
    const int rb = blockIdx.x, t = threadIdx.x;   // 256 blocks x 256 rows
    float s1a = 0, s2a = 0, s1b = 0, s2b = 0;
    for (int r = 0; r < 256; ++r) {
        const unsigned* hp = (const unsigned*)(H + (size_t)(rb * 256 + r) * 512);
        unsigned u = hp[t];
        float lo = __uint_as_float(u << 16);
        float hi = __uint_as_float(u & 0xffff0000u);
        s1a += lo; s2a = fmaf(lo, lo, s2a);
        s1b += hi; s2b = fmaf(hi, hi, s2b);
    }
    P1[rb * 512 + 2 * t] = s1a; P1[rb * 512 + 2 * t + 1] = s1b;
    P2[rb * 512 + 2 * t] = s2a; P2[rb * 512 + 2 * t + 1] = s2b;
}

__global__ __launch_bounds__(512)
void td_bnfin(const float* __restrict__ P1, const float* __restrict__ P2,
              const float* __restrict__ gamma, const float* __restrict__ beta,
              float* __restrict__ SS) {
    const int ch = threadIdx.x;
    float s1 = 0, s2 = 0;
    for (int rb = 0; rb < 256; ++rb) { s1 += P1[rb * 512 + ch]; s2 += P2[rb * 512 + ch]; }
    const float invN = 1.0f / 65536.0f;
    float mu  = s1 * invN;
    float var = s2 * invN - mu * mu;
    float sc  = gamma[ch] * (1.0f / sqrtf(var + 1e-5f));
    float sh  = beta[ch] - mu * sc;
    SS[ch] = sc; SS[512 + ch] = sh;
}

// ---------------------------------------------------------------------------
// KNN via MFMA, fp16 split (hi/lo), 3-pass: S = QhXh + QhXl + QlXh.
// Grid 512 = 16 clouds x 8 q-groups(128q) x 4 candidate segments(1024c).
// bx&15 = cloud => cloud's blocks share an XCD slice (L2 locality on X).
// Block 256 thr = 4 waves; wave owns 32 q (2 subtiles of 16), Q frags in
// 128 VGPRs -> 2 waves/SIMD, 2 blocks/CU. Candidates staged 32/chunk in LDS.
// Per-thread (t<128) exact top-16 over its segment, sorted (d asc, idx asc).
// ---------------------------------------------------------------------------
__global__ __launch_bounds__(256, 2)
void td_knn2(const float* __restrict__ feat, const float* __restrict__ XX,
             const int* __restrict__ FPSI, float* __restrict__ PD,
             int* __restrict__ PI) {
    __shared__ union {
        _Float16 x[2][32][264];   // [hi/lo][c][k], row pad 8 halfs
        float    dt[128][33];     // aliased after MFMA: d values [q_local][c_local]
    } sm;
    __shared__ float QQs[128];
    __shared__ int   QR[128];

    const int bx = blockIdx.x, t = threadIdx.x;
    const int b = bx & 15, r2 = bx >> 4;          // r2 in [0,32)
    const int qq8 = r2 >> 2, seg = r2 & 3;
    const int cb = b * TD_P;
    const int segbase = cb + seg * 1024;

    if (t < 128) {   // query rows + norms
        int gr = FPSI[b * TD_S + qq8 * 128 + t];
        QR[t] = gr; QQs[t] = XX[gr];
    }
    __syncthreads();

    const int w = t >> 6, lane = t & 63;
    const int m = lane & 15, quad = lane >> 4;

    // ---- Q fragments into registers (A-op: lane holds Q[m][quad*8+j]) ------
    half8 qh[2][8], ql[2][8];
#pragma unroll
    for (int qs = 0; qs < 2; ++qs) {
        const float* qp = feat + (size_t)QR[w * 32 + qs * 16 + m] * 256;
#pragma unroll
        for (int ks = 0; ks < 8; ++ks) {
            float4 f0 = *(const float4*)(qp + ks * 32 + quad * 8);
            float4 f1 = *(const float4*)(qp + ks * 32 + quad * 8 + 4);
            float fv[8] = {f0.x, f0.y, f0.z, f0.w, f1.x, f1.y, f1.z, f1.w};
            half8 h, l;
#pragma unroll
            for (int j = 0; j < 8; ++j) {
                _Float16 hv = (_Float16)fv[j];
                h[j] = hv;
                l[j] = (_Float16)(fv[j] - (float)hv);
            }
            qh[qs][ks] = h; ql[qs][ks] = l;
        }
    }

    float sd[16]; int si[16];
#pragma unroll
    for (int r = 0; r < 16; ++r) { sd[r] = __builtin_inff(); si[r] = 0x7fffffff; }

    const int xrow = t >> 3, part = t & 7;   // staging mapping

    for (int ct = 0; ct < 32; ++ct) {
        __syncthreads();   // prev selection done reading dt (aliases x)
        // ---- stage 32 candidates x 256 k, fp32 -> fp16 hi/lo ---------------
        {
            const float* xp = feat + (size_t)(segbase + ct * 32 + xrow) * 256 + part * 32;
#pragma unroll
            for (int s2 = 0; s2 < 4; ++s2) {
                float4 f0 = *(const float4*)(xp + s2 * 8);
                float4 f1 = *(const float4*)(xp + s2 * 8 + 4);
                float fv[8] = {f0.x, f0.y, f0.z, f0.w, f1.x, f1.y, f1.z, f1.w};
                half8 h, l;
#pragma unroll
                for (int j = 0; j < 8; ++j) {
                    _Float16 hv = (_Float16)fv[j];
                    h[j] = hv;
                    l[j] = (_Float16)(fv[j] - (float)hv);
                }
                *(half8*)&sm.x[0][xrow][part * 32 + s2 * 8] = h;
                *(half8*)&sm.x[1][xrow][part * 32 + s2 * 8] = l;
            }
        }
        __syncthreads();
        // ---- MFMA: acc[qs][cs] over K=256 ---------------------------------
        f32x4 acc[2][2];
#pragma unroll
        for (int qs = 0; qs < 2; ++qs) { acc[qs][0] = (f32x4)0.0f; acc[qs][1] = (f32x4)0.0f; }
#pragma unroll
        for (int ks = 0; ks < 8; ++ks) {
            half8 xh0 = *(half8*)&sm.x[0][m][ks * 32 + quad * 8];
            half8 xl0 = *(half8*)&sm.x[1][m][ks * 32 + quad * 8];
            half8 xh1 = *(half8*)&sm.x[0][16 + m][ks * 32 + quad * 8];
            half8 xl1 = *(half8*)&sm.x[1][16 + m][ks * 32 + quad * 8];
#pragma unroll
            for (int qs = 0; qs < 2; ++qs) {
                acc[qs][0] = __builtin_amdgcn_mfma_f32_16x16x32_f16(ql[qs][ks], xh0, acc[qs][0], 0, 0, 0);
                acc[qs][0] = __builtin_amdgcn_mfma_f32_16x16x32_f16(qh[qs][ks], xl0, acc[qs][0], 0, 0, 0);
                acc[qs][0] = __builtin_amdgcn_mfma_f32_16x16x32_f16(qh[qs][ks], xh0, acc[qs][0], 0, 0, 0);
                acc[qs][1] = __builtin_amdgcn_mfma_f32_16x16x32_f16(ql[qs][ks], xh1, acc[qs][1], 0, 0, 0);
                acc[qs][1] = __builtin_amdgcn_mfma_f32_16x16x32_f16(qh[qs][ks], xl1, acc[qs][1], 0, 0, 0);
                acc[qs][1] = __builtin_amdgcn_mfma_f32_16x16x32_f16(qh[qs][ks], xh1, acc[qs][1], 0, 0, 0);
            }
        }
        __syncthreads();   // all waves done reading x; safe to alias as dt
        // ---- epilogue: d = (qq - 2S) + xx, dump to dt ----------------------
        {
            float xx0 = XX[segbase + ct * 32 + m];
            float xx1 = XX[segbase + ct * 32 + 16 + m];
#pragma unroll
            for (int qs = 0; qs < 2; ++qs) {
                int qb = w * 32 + qs * 16 + quad * 4;
#pragma unroll
                for (int reg = 0; reg < 4; ++reg) {
                    float qq = QQs[qb + reg];
                    sm.dt[qb + reg][m]      = (qq - 2.0f * acc[qs][0][reg]) + xx0;
                    sm.dt[qb + reg][16 + m] = (qq - 2.0f * acc[qs][1][reg]) + xx1;
                }
            }
        }
        __syncthreads();
        // ---- selection: thread t (<128) owns query t, scans 32 candidates --
        if (t < 128) {
            const int ibase = segbase + ct * 32;
            for (int j = 0; j < 32; ++j) {
                float d = sm.dt[t][j];
                if (d < sd[15]) {
                    sd[15] = d; si[15] = ibase + j;   // ascending idx => strict < ok
#pragma unroll
                    for (int r = 15; r > 0; --r) {
                        if (sd[r] < sd[r - 1]) {
                            float td2 = sd[r]; sd[r] = sd[r - 1]; sd[r - 1] = td2;
                            int ti = si[r]; si[r] = si[r - 1]; si[r - 1] = ti;
                        }
                    }
                }
            }
        }
    }
    // ---- write sorted per-segment partial top-16 ---------------------------
    if (t < 128) {
        size_t o = ((size_t)(b * TD_S + qq8 * 128 + t)) * 64 + seg * 16;
#pragma unroll
        for (int r = 0; r < 16; ++r) { PD[o + r] = sd[r]; PI[o + r] = si[r]; }
    }
}

// Exact 4-way merge of sorted segment partials -> final top-16 per query.
__global__ __launch_bounds__(64)
void td_merge(const float* __restrict__ PD, const int* __restrict__ PI,
              int* __restrict__ NN) {
    __shared__ float ld_[64][65];
    __shared__ int   li_[64][65];
    const int bx = blockIdx.x, t = threadIdx.x;
    for (int j = 0; j < 64; ++j) {
        ld_[j][t] = PD[(size_t)bx * 4096 + j * 64 + t];
        li_[j][t] = PI[(size_t)bx * 4096 + j * 64 + t];
    }
    __syncthreads();
    int p[4] = {0, 0, 0, 0};
    int og = (bx * 64 + t) * TD_K;
    for (int r = 0; r < 16; ++r) {
        float bd = __builtin_inff(); int bi = 0x7fffffff; int bs = 0;
#pragma unroll
        for (int s = 0; s < 4; ++s) {
            if (p[s] < 16) {
                float d = ld_[t][s * 16 + p[s]];
                int   i = li_[t][s * 16 + p[s]];
                if (d < bd || (d == bd && i < bi)) { bd = d; bi = i; bs = s; }
            }
        }
        p[bs]++;
        NN[og + r] = bi;
    }
}

__global__ __launch_bounds__(256)
void td_maxpool(const unsigned short* __restrict__ H, const int* __restrict__ NN,
                const float* __restrict__ SS, float* __restrict__ outF) {
    __shared__ int nbr[16];
    const int g = blockIdx.x, t = threadIdx.x;
    if (t < 16) nbr[t] = NN[g * 16 + t];
    __syncthreads();
    float sc0 = SS[2 * t], sc1 = SS[2 * t + 1];
    float sh0 = SS[512 + 2 * t], sh1 = SS[512 + 2 * t + 1];
    float m0 = 0.0f, m1 = 0.0f;   // relu floor: max_k relu(v) = max(0, max_k v)
#pragma unroll
    for (int k = 0; k < 16; ++k) {
        int row = nbr[k];
        unsigned u = ((const unsigned*)(H + (size_t)row * 512))[t];
        float lo = __uint_as_float(u << 16);
        float hi = __uint_as_float(u & 0xffff0000u);
        m0 = fmaxf(m0, fmaf(sc0, lo, sh0));
        m1 = fmaxf(m1, fmaf(sc1, hi, sh1));
    }
    float2 o; o.x = m0; o.y = m1;
    *(float2*)&outF[(size_t)g * 512 + 2 * t] = o;
}

extern "C" void kernel_launch(void* const* d_in, const int* in_sizes, int n_in,
                              void* d_out, int out_size, void* d_ws, size_t ws_size,
                              hipStream_t stream) {
    const float* feat  = (const float*)d_in[0];
    const float* pos   = (const float*)d_in[1];
    // d_in[2] = batch (int32): unused, value is row/P by construction
    const float* W     = (const float*)d_in[3];
    const float* bias  = (const float*)d_in[4];
    const float* gamma = (const float*)d_in[5];
    const float* beta  = (const float*)d_in[6];

    char* ws = (char*)d_ws;
    unsigned short* H = (unsigned short*)ws;            // 67,108,864 B (bf16 h)
    float* XX  = (float*)(ws + 67108864);               //    262,144 B
    int*   FPSI= (int*)  (ws + 67371008);               //     65,536 B
    int*   NN  = (int*)  (ws + 67436544);               //  1,048,576 B
    float* P1  = (float*)(ws + 68485120);               //    524,288 B used
    float* P2  = (float*)(ws + 69533696);               //    524,288 B used
    float* SS  = (float*)(ws + 70582272);               //      4,096 B
    float* PD  = (float*)(ws + 70586368);               //  4,194,304 B
    int*   PI  = (int*)  (ws + 74780672);               //  4,194,304 B

    float* outF = (float*)d_out;
    float* outP = outF + (size_t)TD_B * TD_S * TD_OUTF;   // 8,388,608
    float* outB = outP + (size_t)TD_B * TD_S * 3;         // +49,152

    td_fused  <<<2064, 512, 0, stream>>>(feat, pos, W, bias, H, XX, FPSI, outP, outB);
    td_stats  <<<256, 256, 0, stream>>>(H, P1, P2);
    td_bnfin  <<<1, 512, 0, stream>>>(P1, P2, gamma, beta, SS);
    td_knn2   <<<512, 256, 0, stream>>>(feat, XX, FPSI, PD, PI);
    td_merge  <<<256, 64, 0, stream>>>(PD, PI, NN);
    td_maxpool<<<TD_B * TD_S, 256, 0, stream>>>(H, NN, SS, outF);
}

// Round 5
// 1116.803 us; speedup vs baseline: 2.1769x; 1.0276x over previous
//
#include <hip/hip_runtime.h>
#include <cstddef>

// TransitionDown: B=16 clouds, P=4096 pts, S=1024 fps samples, K=16 knn,
// IN_F=256, OUT_F=512.
// Pipeline:
//   L1 fused: blocks[0,16)   FPS per cloud (np-bitwise fp32, no FMA),
//                            64-bit DPP wave-argmax, 1 barrier/step.
//                            LDS padded to 84KB -> 1 block/CU so FPS owns
//                            its CU (no GEMM LDS-pipe contention).
//             blocks[16,1040) MLP GEMM fp32 -> h bf16 (hidden under FPS)
//             blocks[1040,2064) xx[i] = ||features_i||^2
//   L2: BN partial sums over h   L3: BN finalize -> scale/shift
//   L4: KNN via fp16-split MFMA (S = QhXh + QhXl + QlXh), per-segment top-16
//   L5: exact 4-way merge of segment partials -> NN
//   L6: gather + BN + ReLU + max over K (cloud-grouped for L2 locality)

#define TD_B   16
#define TD_P   4096
#define TD_S   1024
#define TD_K   16
#define TD_INF 256
#define TD_OUTF 512

typedef __attribute__((ext_vector_type(8))) _Float16 half8;
typedef __attribute__((ext_vector_type(4))) float    f32x4;

__device__ __forceinline__ unsigned short f2bf(float x) {
    unsigned u = __float_as_uint(x);
    unsigned r = (u + 0x7fffu + ((u >> 16) & 1u)) >> 16;   // RNE
    return (unsigned short)r;
}

struct FpsSm {
    float4 p4[TD_P];      // 64 KB: (x,y,z,-) per point, b128 winner read
    int    sel[TD_S];
    unsigned long long kw[2][8];   // parity-buffered per-wave argmax keys
};
struct GemmSm {
    float As[16 * 260];   // [k][m]
    float Bs[16 * 128];   // [k][n]
};
union SmU {
    FpsSm f; GemmSm g;
    char pad_[84000];     // force 1 block/CU (2x84000 > 160KB LDS):
                          // FPS latency chain must not share the LDS pipe
                          // with a GEMM block's bulk ds traffic.
};

// One level of a wave64 max-reduce on a u64 key via paired 32-bit DPP +
// v_cmp_gt_u64. Result valid in lane 63 after shr 1,2,4,8 + bcast15 + bcast31.
#define TD_DPPSTEP(k, ctl, bc)                                                          \
    {                                                                                   \
        unsigned yh_ = (unsigned)__builtin_amdgcn_update_dpp(                           \
            0, (int)(unsigned)((k) >> 32), (ctl), 0xf, 0xf, (bc));                      \
        unsigned yl_ = (unsigned)__builtin_amdgcn_update_dpp(                           \
            0, (int)(unsigned)(k), (ctl), 0xf, 0xf, (bc));                              \
        unsigned long long y_ = ((unsigned long long)yh_ << 32) | yl_;                  \
        if (y_ > (k)) (k) = y_;                                                         \
    }

__global__ __launch_bounds__(512)
void td_fused(const float* __restrict__ feat, const float* __restrict__ pos,
              const float* __restrict__ W, const float* __restrict__ bias,
              unsigned short* __restrict__ H, float* __restrict__ XX,
              int* __restrict__ FPSI, float* __restrict__ outP,
              float* __restrict__ outB) {
    __shared__ SmU sm;
    const int bx = blockIdx.x;
    const int t  = threadIdx.x;

    if (bx < 16) {
        // ---------------- FPS: one block per cloud, private CU ---------------
        // key = u64 (hi = fp32 bits of min_d, lo = ~p): max => largest d,
        // tie -> lowest p. In-thread: f64 fmax tree (valid positive doubles).
        // Cross-lane: 64-bit DPP butterfly, lane 63 writes wave key to LDS.
        // Cross-wave: broadcast merge of 8 keys as f64 fmax.
        __builtin_amdgcn_s_setprio(2);
        const int b = bx;
        const int w = t >> 6;
        float px[8], py[8], pz[8], md[8];
        int ni[8];
#pragma unroll
        for (int j = 0; j < 8; ++j) {
            int p = j * 512 + t;
            const float* pp = pos + (size_t)(b * TD_P + p) * 3;
            float x = pp[0], y = pp[1], z = pp[2];
            px[j] = x; py[j] = y; pz[j] = z;
            sm.f.p4[p] = make_float4(x, y, z, 0.0f);
            md[j] = __builtin_inff();
            ni[j] = ~p;
        }
        if (t == 0) sm.f.sel[0] = 0;
        __syncthreads();
        float lx = sm.f.p4[0].x, ly = sm.f.p4[0].y, lz = sm.f.p4[0].z;
        for (int s = 0; s < TD_S - 1; ++s) {
            double k[8];
#pragma unroll
            for (int j = 0; j < 8; ++j) {
                // exact np order: sub, sq, sq, sq, add, add, min (no contraction)
                float dx = __fsub_rn(px[j], lx);
                float dy = __fsub_rn(py[j], ly);
                float dz = __fsub_rn(pz[j], lz);
                float d  = __fadd_rn(__fadd_rn(__fmul_rn(dx, dx), __fmul_rn(dy, dy)),
                                     __fmul_rn(dz, dz));
                float m  = fminf(md[j], d);
                md[j] = m;
                k[j] = __hiloint2double(__float_as_int(m), ni[j]);
            }
            double k01 = fmax(k[0], k[1]), k23 = fmax(k[2], k[3]);
            double k45 = fmax(k[4], k[5]), k67 = fmax(k[6], k[7]);
            double kk  = fmax(fmax(k01, k23), fmax(k45, k67));
            unsigned long long tk = (unsigned long long)__double_as_longlong(kk);
            TD_DPPSTEP(tk, 0x111, true)    // row_shr:1
            TD_DPPSTEP(tk, 0x112, true)    // row_shr:2
            TD_DPPSTEP(tk, 0x114, true)    // row_shr:4
            TD_DPPSTEP(tk, 0x118, true)    // row_shr:8
            TD_DPPSTEP(tk, 0x142, false)   // row_bcast:15
            TD_DPPSTEP(tk, 0x143, false)   // row_bcast:31
            const int par = s & 1;
            if ((t & 63) == 63) sm.f.kw[par][w] = tk;   // lane 63 holds wave max
            __syncthreads();
            const unsigned long long* kwp = sm.f.kw[par];
            double g01 = fmax(__longlong_as_double((long long)kwp[0]),
                              __longlong_as_double((long long)kwp[1]));
            double g23 = fmax(__longlong_as_double((long long)kwp[2]),
                              __longlong_as_double((long long)kwp[3]));
            double g45 = fmax(__longlong_as_double((long long)kwp[4]),
                              __longlong_as_double((long long)kwp[5]));
            double g67 = fmax(__longlong_as_double((long long)kwp[6]),
                              __longlong_as_double((long long)kwp[7]));
            double gk  = fmax(fmax(g01, g23), fmax(g45, g67));
            unsigned idx = ~(unsigned)__double2loint(gk);
            if (t == 0) sm.f.sel[s + 1] = (int)idx;
            float4 wp = sm.f.p4[idx];
            lx = wp.x; ly = wp.y; lz = wp.z;
        }
        __syncthreads();
        for (int s = t; s < TD_S; s += 512) {
            int li = sm.f.sel[s];
            int og = b * TD_S + s;
            float4 wp = sm.f.p4[li];
            outP[og * 3 + 0] = wp.x;
            outP[og * 3 + 1] = wp.y;
            outP[og * 3 + 2] = wp.z;
            outB[og] = (float)b;
            FPSI[og] = b * TD_P + li;   // global row index
        }
    } else if (bx < 16 + 1024) {
        // ---------------- MLP GEMM: 256x128 tile, 512 thr, 8x8 micro ---------
        const int gb = bx - 16;
        const int mb = gb >> 2, nb = gb & 3;
        const int tm = t >> 4, tn = t & 15;
        float acc[8][8];
#pragma unroll
        for (int i = 0; i < 8; ++i)
#pragma unroll
            for (int j = 0; j < 8; ++j) acc[i][j] = 0.0f;
        float* As = sm.g.As;
        float* Bs = sm.g.Bs;
        for (int kc = 0; kc < 16; ++kc) {
#pragma unroll
            for (int p2 = 0; p2 < 2; ++p2) {
                int f4 = t + 512 * p2;
                int r = f4 >> 2, c4 = f4 & 3;
                float4 v = *(const float4*)&feat[(size_t)(mb * 256 + r) * 256 + kc * 16 + c4 * 4];
                As[(c4 * 4 + 0) * 260 + r] = v.x;
                As[(c4 * 4 + 1) * 260 + r] = v.y;
                As[(c4 * 4 + 2) * 260 + r] = v.z;
                As[(c4 * 4 + 3) * 260 + r] = v.w;
            }
            {
                int kk = t >> 5, n4 = t & 31;
                float4 v = *(const float4*)&W[(size_t)(kc * 16 + kk) * 512 + nb * 128 + n4 * 4];
                *(float4*)&Bs[kk * 128 + n4 * 4] = v;
            }
            __syncthreads();
#pragma unroll
            for (int kk = 0; kk < 16; ++kk) {
                float4 a0 = *(float4*)&As[kk * 260 + tm * 8];
                float4 a1 = *(float4*)&As[kk * 260 + tm * 8 + 4];
                float4 b0 = *(float4*)&Bs[kk * 128 + tn * 8];
                float4 b1 = *(float4*)&Bs[kk * 128 + tn * 8 + 4];
                float av[8] = {a0.x, a0.y, a0.z, a0.w, a1.x, a1.y, a1.z, a1.w};
                float bv2[8] = {b0.x, b0.y, b0.z, b0.w, b1.x, b1.y, b1.z, b1.w};
#pragma unroll
                for (int i = 0; i < 8; ++i)
#pragma unroll
                    for (int j = 0; j < 8; ++j)
                        acc[i][j] = fmaf(av[i], bv2[j], acc[i][j]);
            }
            __syncthreads();
        }
        float4 bb0 = *(const float4*)&bias[nb * 128 + tn * 8];
        float4 bb1 = *(const float4*)&bias[nb * 128 + tn * 8 + 4];
        float bsv[8] = {bb0.x, bb0.y, bb0.z, bb0.w, bb1.x, bb1.y, bb1.z, bb1.w};
#pragma unroll
        for (int i = 0; i < 8; ++i) {
            int row = mb * 256 + tm * 8 + i;
            uint4 pk;
            pk.x = (unsigned)f2bf(acc[i][0] + bsv[0]) | ((unsigned)f2bf(acc[i][1] + bsv[1]) << 16);
            pk.y = (unsigned)f2bf(acc[i][2] + bsv[2]) | ((unsigned)f2bf(acc[i][3] + bsv[3]) << 16);
            pk.z = (unsigned)f2bf(acc[i][4] + bsv[4]) | ((unsigned)f2bf(acc[i][5] + bsv[5]) << 16);
            pk.w = (unsigned)f2bf(acc[i][6] + bsv[6]) | ((unsigned)f2bf(acc[i][7] + bsv[7]) << 16);
            *(uint4*)&H[(size_t)row * 512 + nb * 128 + tn * 8] = pk;
        }
    } else {
        // ---------------- xx[i] = ||features_i||^2 ---------------------------
        const int xb = bx - 1040;
        const int w = t >> 6, lane = t & 63;
#pragma unroll
        for (int it = 0; it < 8; ++it) {
            int r = xb * 64 + w * 8 + it;
            float4 v = *(const float4*)&feat[(size_t)r * 256 + lane * 4];
            float s = v.x * v.x + v.y * v.y + v.z * v.z + v.w * v.w;
#pragma unroll
            for (int off = 32; off > 0; off >>= 1) s += __shfl_down(s, off, 64);
            if (lane == 0) XX[r] = s;
        }
    }
}

__global__ __launch_bounds__(256)
void td_stats(const unsigned short* __restrict__ H, float* __restrict__ P1,
              float* __restrict__ P2) {
    const int rb = blockIdx.x, t = threadIdx.x;   // 256 blocks x 256 rows
    float s1a = 0, s2a = 0, s1b = 0, s2b = 0;
    for (int r = 0; r < 256; ++r) {
        const unsigned* hp = (const unsigned*)(H + (size_t)(rb * 256 + r) * 512);
        unsigned u = hp[t];
        float lo = __uint_as_float(u << 16);
        float hi = __uint_as_float(u & 0xffff0000u);
        s1a += lo; s2a = fmaf(lo, lo, s2a);
        s1b += hi; s2b = fmaf(hi, hi, s2b);
    }
    P1[rb * 512 + 2 * t] = s1a; P1[rb * 512 + 2 * t + 1] = s1b;
    P2[rb * 512 + 2 * t] = s2a; P2[rb * 512 + 2 * t + 1] = s2b;
}

__global__ __launch_bounds__(512)
void td_bnfin(const float* __restrict__ P1, const float* __restrict__ P2,
              const float* __restrict__ gamma, const float* __restrict__ beta,
              float* __restrict__ SS) {
    const int ch = threadIdx.x;
    float s1 = 0, s2 = 0;
    for (int rb = 0; rb < 256; ++rb) { s1 += P1[rb * 512 + ch]; s2 += P2[rb * 512 + ch]; }
    const float invN = 1.0f / 65536.0f;
    float mu  = s1 * invN;
    float var = s2 * invN - mu * mu;
    float sc  = gamma[ch] * (1.0f / sqrtf(var + 1e-5f));
    float sh  = beta[ch] - mu * sc;
    SS[ch] = sc; SS[512 + ch] = sh;
}

// ---------------------------------------------------------------------------
// KNN via MFMA, fp16 split (hi/lo), 3-pass: S = QhXh + QhXl + QlXh.
// Grid 512 = 16 clouds x 8 q-groups(128q) x 4 candidate segments(1024c).
// bx&15 = cloud => cloud's blocks share an XCD slice (L2 locality on X).
// Block 256 thr = 4 waves; wave owns 32 q (2 subtiles of 16), Q frags in
// 128 VGPRs -> 2 waves/SIMD, 2 blocks/CU. Candidates staged 32/chunk in LDS.
// Per-thread (t<128) exact top-16 over its segment, sorted (d asc, idx asc).
// ---------------------------------------------------------------------------
__global__ __launch_bounds__(256, 2)
void td_knn2(const float* __restrict__ feat, const float* __restrict__ XX,
             const int* __restrict__ FPSI, float* __restrict__ PD,
             int* __restrict__ PI) {
    __shared__ union {
        _Float16 x[2][32][264];   // [hi/lo][c][k], row pad 8 halfs
        float    dt[128][33];     // aliased after MFMA: d values [q_local][c_local]
    } sm;
    __shared__ float QQs[128];
    __shared__ int   QR[128];

    const int bx = blockIdx.x, t = threadIdx.x;
    const int b = bx & 15, r2 = bx >> 4;          // r2 in [0,32)
    const int qq8 = r2 >> 2, seg = r2 & 3;
    const int cb = b * TD_P;
    const int segbase = cb + seg * 1024;

    if (t < 128) {   // query rows + norms
        int gr = FPSI[b * TD_S + qq8 * 128 + t];
        QR[t] = gr; QQs[t] = XX[gr];
    }
    __syncthreads();

    const int w = t >> 6, lane = t & 63;
    const int m = lane & 15, quad = lane >> 4;

    // ---- Q fragments into registers (A-op: lane holds Q[m][quad*8+j]) ------
    half8 qh[2][8], ql[2][8];
#pragma unroll
    for (int qs = 0; qs < 2; ++qs) {
        const float* qp = feat + (size_t)QR[w * 32 + qs * 16 + m] * 256;
#pragma unroll
        for (int ks = 0; ks < 8; ++ks) {
            float4 f0 = *(const float4*)(qp + ks * 32 + quad * 8);
            float4 f1 = *(const float4*)(qp + ks * 32 + quad * 8 + 4);
            float fv[8] = {f0.x, f0.y, f0.z, f0.w, f1.x, f1.y, f1.z, f1.w};
            half8 h, l;
#pragma unroll
            for (int j = 0; j < 8; ++j) {
                _Float16 hv = (_Float16)fv[j];
                h[j] = hv;
                l[j] = (_Float16)(fv[j] - (float)hv);
            }
            qh[qs][ks] = h; ql[qs][ks] = l;
        }
    }

    float sd[16]; int si[16];
#pragma unroll
    for (int r = 0; r < 16; ++r) { sd[r] = __builtin_inff(); si[r] = 0x7fffffff; }

    const int xrow = t >> 3, part = t & 7;   // staging mapping

    for (int ct = 0; ct < 32; ++ct) {
        __syncthreads();   // prev selection done reading dt (aliases x)
        // ---- stage 32 candidates x 256 k, fp32 -> fp16 hi/lo ---------------
        {
            const float* xp = feat + (size_t)(segbase + ct * 32 + xrow) * 256 + part * 32;
#pragma unroll
            for (int s2 = 0; s2 < 4; ++s2) {
                float4 f0 = *(const float4*)(xp + s2 * 8);
                float4 f1 = *(const float4*)(xp + s2 * 8 + 4);
                float fv[8] = {f0.x, f0.y, f0.z, f0.w, f1.x, f1.y, f1.z, f1.w};
                half8 h, l;
#pragma unroll
                for (int j = 0; j < 8; ++j) {
                    _Float16 hv = (_Float16)fv[j];
                    h[j] = hv;
                    l[j] = (_Float16)(fv[j] - (float)hv);
                }
                *(half8*)&sm.x[0][xrow][part * 32 + s2 * 8] = h;
                *(half8*)&sm.x[1][xrow][part * 32 + s2 * 8] = l;
            }
        }
        __syncthreads();
        // ---- MFMA: acc[qs][cs] over K=256 ---------------------------------
        f32x4 acc[2][2];
#pragma unroll
        for (int qs = 0; qs < 2; ++qs) { acc[qs][0] = (f32x4)0.0f; acc[qs][1] = (f32x4)0.0f; }
#pragma unroll
        for (int ks = 0; ks < 8; ++ks) {
            half8 xh0 = *(half8*)&sm.x[0][m][ks * 32 + quad * 8];
            half8 xl0 = *(half8*)&sm.x[1][m][ks * 32 + quad * 8];
            half8 xh1 = *(half8*)&sm.x[0][16 + m][ks * 32 + quad * 8];
            half8 xl1 = *(half8*)&sm.x[1][16 + m][ks * 32 + quad * 8];
#pragma unroll
            for (int qs = 0; qs < 2; ++qs) {
                acc[qs][0] = __builtin_amdgcn_mfma_f32_16x16x32_f16(ql[qs][ks], xh0, acc[qs][0], 0, 0, 0);
                acc[qs][0] = __builtin_amdgcn_mfma_f32_16x16x32_f16(qh[qs][ks], xl0, acc[qs][0], 0, 0, 0);
                acc[qs][0] = __builtin_amdgcn_mfma_f32_16x16x32_f16(qh[qs][ks], xh0, acc[qs][0], 0, 0, 0);
                acc[qs][1] = __builtin_amdgcn_mfma_f32_16x16x32_f16(ql[qs][ks], xh1, acc[qs][1], 0, 0, 0);
                acc[qs][1] = __builtin_amdgcn_mfma_f32_16x16x32_f16(qh[qs][ks], xl1, acc[qs][1], 0, 0, 0);
                acc[qs][1] = __builtin_amdgcn_mfma_f32_16x16x32_f16(qh[qs][ks], xh1, acc[qs][1], 0, 0, 0);
            }
        }
        __syncthreads();   // all waves done reading x; safe to alias as dt
        // ---- epilogue: d = (qq - 2S) + xx, dump to dt ----------------------
        {
            float xx0 = XX[segbase + ct * 32 + m];
            float xx1 = XX[segbase + ct * 32 + 16 + m];
#pragma unroll
            for (int qs = 0; qs < 2; ++qs) {
                int qb = w * 32 + qs * 16 + quad * 4;
#pragma unroll
                for (int reg = 0; reg < 4; ++reg) {
                    float qq = QQs[qb + reg];
                    sm.dt[qb + reg][m]      = (qq - 2.0f * acc[qs][0][reg]) + xx0;
                    sm.dt[qb + reg][16 + m] = (qq - 2.0f * acc[qs][1][reg]) + xx1;
                }
            }
        }
        __syncthreads();
        // ---- selection: thread t (<128) owns query t, scans 32 candidates --
        if (t < 128) {
            const int ibase = segbase + ct * 32;
            for (int j = 0; j < 32; ++j) {
                float d = sm.dt[t][j];
                if (d < sd[15]) {
                    sd[15] = d; si[15] = ibase + j;   // ascending idx => strict < ok
#pragma unroll
                    for (int r = 15; r > 0; --r) {
                        if (sd[r] < sd[r - 1]) {
                            float td2 = sd[r]; sd[r] = sd[r - 1]; sd[r - 1] = td2;
                            int ti = si[r]; si[r] = si[r - 1]; si[r - 1] = ti;
                        }
                    }
                }
            }
        }
    }
    // ---- write sorted per-segment partial top-16 ---------------------------
    if (t < 128) {
        size_t o = ((size_t)(b * TD_S + qq8 * 128 + t)) * 64 + seg * 16;
#pragma unroll
        for (int r = 0; r < 16; ++r) { PD[o + r] = sd[r]; PI[o + r] = si[r]; }
    }
}

// Exact 4-way merge of sorted segment partials -> final top-16 per query.
__global__ __launch_bounds__(64)
void td_merge(const float* __restrict__ PD, const int* __restrict__ PI,
              int* __restrict__ NN) {
    __shared__ float ld_[64][65];
    __shared__ int   li_[64][65];
    const int bx = blockIdx.x, t = threadIdx.x;
    for (int j = 0; j < 64; ++j) {
        ld_[j][t] = PD[(size_t)bx * 4096 + j * 64 + t];
        li_[j][t] = PI[(size_t)bx * 4096 + j * 64 + t];
    }
    __syncthreads();
    int p[4] = {0, 0, 0, 0};
    int og = (bx * 64 + t) * TD_K;
    for (int r = 0; r < 16; ++r) {
        float bd = __builtin_inff(); int bi = 0x7fffffff; int bs = 0;
#pragma unroll
        for (int s = 0; s < 4; ++s) {
            if (p[s] < 16) {
                float d = ld_[t][s * 16 + p[s]];
                int   i = li_[t][s * 16 + p[s]];
                if (d < bd || (d == bd && i < bi)) { bd = d; bi = i; bs = s; }
            }
        }
        p[bs]++;
        NN[og + r] = bi;
    }
}

__global__ __launch_bounds__(256)
void td_maxpool(const unsigned short* __restrict__ H, const int* __restrict__ NN,
                const float* __restrict__ SS, float* __restrict__ outF) {
    __shared__ int nbr[16];
    const int bx = blockIdx.x, t = threadIdx.x;
    // cloud-grouped swizzle: consecutive blocks -> same cloud stays on one
    // XCD slice (round-robin dispatch), 4x avg row reuse becomes L2-local.
    const int g = (bx & 15) * 1024 + (bx >> 4);
    if (t < 16) nbr[t] = NN[g * 16 + t];
    __syncthreads();
    float sc0 = SS[2 * t], sc1 = SS[2 * t + 1];
    float sh0 = SS[512 + 2 * t], sh1 = SS[512 + 2 * t + 1];
    float m0 = 0.0f, m1 = 0.0f;   // relu floor: max_k relu(v) = max(0, max_k v)
#pragma unroll
    for (int k = 0; k < 16; ++k) {
        int row = nbr[k];
        unsigned u = ((const unsigned*)(H + (size_t)row * 512))[t];
        float lo = __uint_as_float(u << 16);
        float hi = __uint_as_float(u & 0xffff0000u);
        m0 = fmaxf(m0, fmaf(sc0, lo, sh0));
        m1 = fmaxf(m1, fmaf(sc1, hi, sh1));
    }
    float2 o; o.x = m0; o.y = m1;
    *(float2*)&outF[(size_t)g * 512 + 2 * t] = o;
}

extern "C" void kernel_launch(void* const* d_in, const int* in_sizes, int n_in,
                              void* d_out, int out_size, void* d_ws, size_t ws_size,
                              hipStream_t stream) {
    const float* feat  = (const float*)d_in[0];
    const float* pos   = (const float*)d_in[1];
    // d_in[2] = batch (int32): unused, value is row/P by construction
    const float* W     = (const float*)d_in[3];
    const float* bias  = (const float*)d_in[4];
    const float* gamma = (const float*)d_in[5];
    const float* beta  = (const float*)d_in[6];

    char* ws = (char*)d_ws;
    unsigned short* H = (unsigned short*)ws;            // 67,108,864 B (bf16 h)
    float* XX  = (float*)(ws + 67108864);               //    262,144 B
    int*   FPSI= (int*)  (ws + 67371008);               //     65,536 B
    int*   NN  = (int*)  (ws + 67436544);               //  1,048,576 B
    float* P1  = (float*)(ws + 68485120);               //    524,288 B used
    float* P2  = (float*)(ws + 69533696);               //    524,288 B used
    float* SS  = (float*)(ws + 70582272);               //      4,096 B
    float* PD  = (float*)(ws + 70586368);               //  4,194,304 B
    int*   PI  = (int*)  (ws + 74780672);               //  4,194,304 B

    float* outF = (float*)d_out;
    float* outP = outF + (size_t)TD_B * TD_S * TD_OUTF;   // 8,388,608
    float* outB = outP + (size_t)TD_B * TD_S * 3;         // +49,152

    td_fused  <<<2064, 512, 0, stream>>>(feat, pos, W, bias, H, XX, FPSI, outP, outB);
    td_stats  <<<256, 256, 0, stream>>>(H, P1, P2);
    td_bnfin  <<<1, 512, 0, stream>>>(P1, P2, gamma, beta, SS);
    td_knn2   <<<512, 256, 0, stream>>>(feat, XX, FPSI, PD, PI);
    td_merge  <<<256, 64, 0, stream>>>(PD, PI, NN);
    td_maxpool<<<TD_B * TD_S, 256, 0, stream>>>(H, NN, SS, outF);
}

// Round 6
// 1107.201 us; speedup vs baseline: 2.1958x; 1.0087x over previous
//
#include <hip/hip_runtime.h>
#include <cstddef>

// TransitionDown: B=16 clouds, P=4096 pts, S=1024 fps samples, K=16 knn,
// IN_F=256, OUT_F=512.
// Pipeline:
//   L1 fused: blocks[0,16)   FPS per cloud (np-bitwise fp32, contract off),
//                            256 active thr (1 wave/SIMD), packed v2f math,
//                            64-bit DPP wave-argmax, 1 barrier/step.
//             blocks[16,1040) MLP GEMM fp32 -> h bf16 (hidden under FPS)
//             blocks[1040,2064) xx[i] = ||features_i||^2
//   L2: BN partial sums over h   L3: BN finalize -> scale/shift
//   L4: KNN via fp16-split MFMA (S = QhXh + QhXl + QlXh), per-segment top-16
//   L5: exact 4-way merge of segment partials -> NN
//   L6: gather + BN + ReLU + max over K (4 queries/block, cloud-grouped)

#define TD_B   16
#define TD_P   4096
#define TD_S   1024
#define TD_K   16
#define TD_INF 256
#define TD_OUTF 512

typedef __attribute__((ext_vector_type(8))) _Float16 half8;
typedef __attribute__((ext_vector_type(4))) float    f32x4;
typedef __attribute__((ext_vector_type(2))) float    v2f;

__device__ __forceinline__ unsigned short f2bf(float x) {
    unsigned u = __float_as_uint(x);
    unsigned r = (u + 0x7fffu + ((u >> 16) & 1u)) >> 16;   // RNE
    return (unsigned short)r;
}

struct FpsSm {
    float4 p4[TD_P];      // 64 KB: (x,y,z,-) per point, b128 winner read
    int    sel[TD_S];
    unsigned long long kw[2][8];   // parity-buffered per-wave argmax keys
};
struct GemmSm {
    float As[16 * 260];   // [k][m]
    float Bs[16 * 128];   // [k][n]
};
union SmU {
    FpsSm f; GemmSm g;
    char pad_[84000];     // 1 block/CU: FPS keeps a private CU
};

// One level of a wave64 max-reduce on a u64 key via paired 32-bit DPP +
// 64-bit compare. Result valid in lane 63 after shr 1,2,4,8 + bcast15 + bcast31.
#define TD_DPPSTEP(k, ctl, bc)                                                          \
    {                                                                                   \
        unsigned yh_ = (unsigned)__builtin_amdgcn_update_dpp(                           \
            0, (int)(unsigned)((k) >> 32), (ctl), 0xf, 0xf, (bc));                      \
        unsigned yl_ = (unsigned)__builtin_amdgcn_update_dpp(                           \
            0, (int)(unsigned)(k), (ctl), 0xf, 0xf, (bc));                              \
        unsigned long long y_ = ((unsigned long long)yh_ << 32) | yl_;                  \
        if (y_ > (k)) (k) = y_;                                                         \
    }

__global__ __launch_bounds__(512)
void td_fused(const float* __restrict__ feat, const float* __restrict__ pos,
              const float* __restrict__ W, const float* __restrict__ bias,
              unsigned short* __restrict__ H, float* __restrict__ XX,
              int* __restrict__ FPSI, float* __restrict__ outP,
              float* __restrict__ outB) {
    __shared__ SmU sm;
    const int bx = blockIdx.x;
    const int t  = threadIdx.x;

    if (bx < 16) {
        // ---------------- FPS: one block per cloud, private CU ---------------
        // Only t<256 active (1 wave/SIMD owns the full issue port); 16 pts per
        // thread as 8 packed v2f lanes (v_pk_* fp32, contract off => np-bitwise
        // sub,sq,sq,sq,add,add,min per element). key = u64(hi=fp32 bits of
        // min_d, lo=~p): max => largest d, tie -> lowest p.
        __builtin_amdgcn_s_setprio(2);
        const int b = bx;
        const int w = t >> 6;
        v2f px[8], py[8], pz[8], md[8];
        int ni0[8], ni1[8];
        float lx = 0.0f, ly = 0.0f, lz = 0.0f;
        if (t < 256) {
#pragma unroll
            for (int j = 0; j < 8; ++j) {
                int p0 = j * 512 + t, p1 = p0 + 256;
                const float* q0 = pos + (size_t)(b * TD_P + p0) * 3;
                const float* q1 = pos + (size_t)(b * TD_P + p1) * 3;
                float x0 = q0[0], y0 = q0[1], z0 = q0[2];
                float x1 = q1[0], y1 = q1[1], z1 = q1[2];
                px[j] = (v2f){x0, x1}; py[j] = (v2f){y0, y1}; pz[j] = (v2f){z0, z1};
                sm.f.p4[p0] = make_float4(x0, y0, z0, 0.0f);
                sm.f.p4[p1] = make_float4(x1, y1, z1, 0.0f);
                md[j] = (v2f){__builtin_inff(), __builtin_inff()};
                ni0[j] = ~p0; ni1[j] = ~p1;
            }
            if (t == 0) sm.f.sel[0] = 0;
        }
        __syncthreads();
        if (t < 256) { float4 wp = sm.f.p4[0]; lx = wp.x; ly = wp.y; lz = wp.z; }
        for (int s = 0; s < TD_S - 1; ++s) {
            const int par = s & 1;
            if (t < 256) {
                double k[16];
                {
#pragma clang fp contract(off)
                    v2f l2x = (v2f){lx, lx}, l2y = (v2f){ly, ly}, l2z = (v2f){lz, lz};
#pragma unroll
                    for (int j = 0; j < 8; ++j) {
                        v2f dx = px[j] - l2x;
                        v2f dy = py[j] - l2y;
                        v2f dz = pz[j] - l2z;
                        v2f sx = dx * dx;
                        v2f sy = dy * dy;
                        v2f sz = dz * dz;
                        v2f dd = (sx + sy) + sz;
                        md[j] = __builtin_elementwise_min(md[j], dd);
                        k[2 * j]     = __hiloint2double(__float_as_int(md[j].x), ni0[j]);
                        k[2 * j + 1] = __hiloint2double(__float_as_int(md[j].y), ni1[j]);
                    }
                }
                // in-thread tree (15 v_max_f64)
#pragma unroll
                for (int st = 8; st > 0; st >>= 1)
#pragma unroll
                    for (int i = 0; i < st; ++i) k[i] = fmax(k[i], k[i + st]);
                unsigned long long tk = (unsigned long long)__double_as_longlong(k[0]);
                TD_DPPSTEP(tk, 0x111, true)    // row_shr:1
                TD_DPPSTEP(tk, 0x112, true)    // row_shr:2
                TD_DPPSTEP(tk, 0x114, true)    // row_shr:4
                TD_DPPSTEP(tk, 0x118, true)    // row_shr:8
                TD_DPPSTEP(tk, 0x142, false)   // row_bcast:15
                TD_DPPSTEP(tk, 0x143, false)   // row_bcast:31
                if ((t & 63) == 63) sm.f.kw[par][w] = tk;
            }
            __syncthreads();
            if (t < 256) {
                const unsigned long long* kwp = sm.f.kw[par];
                double g01 = fmax(__longlong_as_double((long long)kwp[0]),
                                  __longlong_as_double((long long)kwp[1]));
                double g23 = fmax(__longlong_as_double((long long)kwp[2]),
                                  __longlong_as_double((long long)kwp[3]));
                double gk  = fmax(g01, g23);
                unsigned idx = ~(unsigned)__double2loint(gk);
                if (t == 0) sm.f.sel[s + 1] = (int)idx;
                float4 wp = sm.f.p4[idx];
                lx = wp.x; ly = wp.y; lz = wp.z;
            }
        }
        __syncthreads();
        for (int s = t; s < TD_S; s += 512) {
            int li = sm.f.sel[s];
            int og = b * TD_S + s;
            float4 wp = sm.f.p4[li];
            outP[og * 3 + 0] = wp.x;
            outP[og * 3 + 1] = wp.y;
            outP[og * 3 + 2] = wp.z;
            outB[og] = (float)b;
            FPSI[og] = b * TD_P + li;   // global row index
        }
    } else if (bx < 16 + 1024) {
        // ---------------- MLP GEMM: 256x128 tile, 512 thr, 8x8 micro ---------
        const int gb = bx - 16;
        const int mb = gb >> 2, nb = gb & 3;
        const int tm = t >> 4, tn = t & 15;
        float acc[8][8];
#pragma unroll
        for (int i = 0; i < 8; ++i)
#pragma unroll
            for (int j = 0; j < 8; ++j) acc[i][j] = 0.0f;
        float* As = sm.g.As;
        float* Bs = sm.g.Bs;
        for (int kc = 0; kc < 16; ++kc) {
#pragma unroll
            for (int p2 = 0; p2 < 2; ++p2) {
                int f4 = t + 512 * p2;
                int r = f4 >> 2, c4 = f4 & 3;
                float4 v = *(const float4*)&feat[(size_t)(mb * 256 + r) * 256 + kc * 16 + c4 * 4];
                As[(c4 * 4 + 0) * 260 + r] = v.x;
                As[(c4 * 4 + 1) * 260 + r] = v.y;
                As[(c4 * 4 + 2) * 260 + r] = v.z;
                As[(c4 * 4 + 3) * 260 + r] = v.w;
            }
            {
                int kk = t >> 5, n4 = t & 31;
                float4 v = *(const float4*)&W[(size_t)(kc * 16 + kk) * 512 + nb * 128 + n4 * 4];
                *(float4*)&Bs[kk * 128 + n4 * 4] = v;
            }
            __syncthreads();
#pragma unroll
            for (int kk = 0; kk < 16; ++kk) {
                float4 a0 = *(float4*)&As[kk * 260 + tm * 8];
                float4 a1 = *(float4*)&As[kk * 260 + tm * 8 + 4];
                float4 b0 = *(float4*)&Bs[kk * 128 + tn * 8];
                float4 b1 = *(float4*)&Bs[kk * 128 + tn * 8 + 4];
                float av[8] = {a0.x, a0.y, a0.z, a0.w, a1.x, a1.y, a1.z, a1.w};
                float bv2[8] = {b0.x, b0.y, b0.z, b0.w, b1.x, b1.y, b1.z, b1.w};
#pragma unroll
                for (int i = 0; i < 8; ++i)
#pragma unroll
                    for (int j = 0; j < 8; ++j)
                        acc[i][j] = fmaf(av[i], bv2[j], acc[i][j]);
            }
            __syncthreads();
        }
        float4 bb0 = *(const float4*)&bias[nb * 128 + tn * 8];
        float4 bb1 = *(const float4*)&bias[nb * 128 + tn * 8 + 4];
        float bsv[8] = {bb0.x, bb0.y, bb0.z, bb0.w, bb1.x, bb1.y, bb1.z, bb1.w};
#pragma unroll
        for (int i = 0; i < 8; ++i) {
            int row = mb * 256 + tm * 8 + i;
            uint4 pk;
            pk.x = (unsigned)f2bf(acc[i][0] + bsv[0]) | ((unsigned)f2bf(acc[i][1] + bsv[1]) << 16);
            pk.y = (unsigned)f2bf(acc[i][2] + bsv[2]) | ((unsigned)f2bf(acc[i][3] + bsv[3]) << 16);
            pk.z = (unsigned)f2bf(acc[i][4] + bsv[4]) | ((unsigned)f2bf(acc[i][5] + bsv[5]) << 16);
            pk.w = (unsigned)f2bf(acc[i][6] + bsv[6]) | ((unsigned)f2bf(acc[i][7] + bsv[7]) << 16);
            *(uint4*)&H[(size_t)row * 512 + nb * 128 + tn * 8] = pk;
        }
    } else {
        // ---------------- xx[i] = ||features_i||^2 ---------------------------
        const int xb = bx - 1040;
        const int w = t >> 6, lane = t & 63;
#pragma unroll
        for (int it = 0; it < 8; ++it) {
            int r = xb * 64 + w * 8 + it;
            float4 v = *(const float4*)&feat[(size_t)r * 256 + lane * 4];
            float s = v.x * v.x + v.y * v.y + v.z * v.z + v.w * v.w;
#pragma unroll
            for (int off = 32; off > 0; off >>= 1) s += __shfl_down(s, off, 64);
            if (lane == 0) XX[r] = s;
        }
    }
}

__global__ __launch_bounds__(256)
void td_stats(const unsigned short* __restrict__ H, float* __restrict__ P1,
              float* __restrict__ P2) {
    const int rb = blockIdx.x, t = threadIdx.x;   // 256 blocks x 256 rows
    float s1a = 0, s2a = 0, s1b = 0, s2b = 0;
    for (int r = 0; r < 256; ++r) {
        const unsigned* hp = (const unsigned*)(H + (size_t)(rb * 256 + r) * 512);
        unsigned u = hp[t];
        float lo = __uint_as_float(u << 16);
        float hi = __uint_as_float(u & 0xffff0000u);
        s1a += lo; s2a = fmaf(lo, lo, s2a);
        s1b += hi; s2b = fmaf(hi, hi, s2b);
    }
    P1[rb * 512 + 2 * t] = s1a; P1[rb * 512 + 2 * t + 1] = s1b;
    P2[rb * 512 + 2 * t] = s2a; P2[rb * 512 + 2 * t + 1] = s2b;
}

__global__ __launch_bounds__(512)
void td_bnfin(const float* __restrict__ P1, const float* __restrict__ P2,
              const float* __restrict__ gamma, const float* __restrict__ beta,
              float* __restrict__ SS) {
    const int ch = threadIdx.x;
    float s1 = 0, s2 = 0;
    for (int rb = 0; rb < 256; ++rb) { s1 += P1[rb * 512 + ch]; s2 += P2[rb * 512 + ch]; }
    const float invN = 1.0f / 65536.0f;
    float mu  = s1 * invN;
    float var = s2 * invN - mu * mu;
    float sc  = gamma[ch] * (1.0f / sqrtf(var + 1e-5f));
    float sh  = beta[ch] - mu * sc;
    SS[ch] = sc; SS[512 + ch] = sh;
}

// ---------------------------------------------------------------------------
// KNN via MFMA, fp16 split (hi/lo), 3-pass: S = QhXh + QhXl + QlXh.
// Grid 512 = 16 clouds x 8 q-groups(128q) x 4 candidate segments(1024c).
// Pass-major MFMA order: 4 independent acc chains, dep distance 4.
// ---------------------------------------------------------------------------
__global__ __launch_bounds__(256, 2)
void td_knn2(const float* __restrict__ feat, const float* __restrict__ XX,
             const int* __restrict__ FPSI, float* __restrict__ PD,
             int* __restrict__ PI) {
    __shared__ union {
        _Float16 x[2][32][264];   // [hi/lo][c][k], row pad 8 halfs
        float    dt[128][33];     // aliased after MFMA: d values [q_local][c_local]
    } sm;
    __shared__ float QQs[128];
    __shared__ int   QR[128];

    const int bx = blockIdx.x, t = threadIdx.x;
    const int b = bx & 15, r2 = bx >> 4;          // r2 in [0,32)
    const int qq8 = r2 >> 2, seg = r2 & 3;
    const int cb = b * TD_P;
    const int segbase = cb + seg * 1024;

    if (t < 128) {   // query rows + norms
        int gr = FPSI[b * TD_S + qq8 * 128 + t];
        QR[t] = gr; QQs[t] = XX[gr];
    }
    __syncthreads();

    const int w = t >> 6, lane = t & 63;
    const int m = lane & 15, quad = lane >> 4;

    // ---- Q fragments into registers (A-op: lane holds Q[m][quad*8+j]) ------
    half8 qh[2][8], ql[2][8];
#pragma unroll
    for (int qs = 0; qs < 2; ++qs) {
        const float* qp = feat + (size_t)QR[w * 32 + qs * 16 + m] * 256;
#pragma unroll
        for (int ks = 0; ks < 8; ++ks) {
            float4 f0 = *(const float4*)(qp + ks * 32 + quad * 8);
            float4 f1 = *(const float4*)(qp + ks * 32 + quad * 8 + 4);
            float fv[8] = {f0.x, f0.y, f0.z, f0.w, f1.x, f1.y, f1.z, f1.w};
            half8 h, l;
#pragma unroll
            for (int j = 0; j < 8; ++j) {
                _Float16 hv = (_Float16)fv[j];
                h[j] = hv;
                l[j] = (_Float16)(fv[j] - (float)hv);
            }
            qh[qs][ks] = h; ql[qs][ks] = l;
        }
    }

    float sd[16]; int si[16];
#pragma unroll
    for (int r = 0; r < 16; ++r) { sd[r] = __builtin_inff(); si[r] = 0x7fffffff; }

    const int xrow = t >> 3, part = t & 7;   // staging mapping

    for (int ct = 0; ct < 32; ++ct) {
        __syncthreads();   // prev selection done reading dt (aliases x)
        // ---- stage 32 candidates x 256 k, fp32 -> fp16 hi/lo ---------------
        {
            const float* xp = feat + (size_t)(segbase + ct * 32 + xrow) * 256 + part * 32;
#pragma unroll
            for (int s2 = 0; s2 < 4; ++s2) {
                float4 f0 = *(const float4*)(xp + s2 * 8);
                float4 f1 = *(const float4*)(xp + s2 * 8 + 4);
                float fv[8] = {f0.x, f0.y, f0.z, f0.w, f1.x, f1.y, f1.z, f1.w};
                half8 h, l;
#pragma unroll
                for (int j = 0; j < 8; ++j) {
                    _Float16 hv = (_Float16)fv[j];
                    h[j] = hv;
                    l[j] = (_Float16)(fv[j] - (float)hv);
                }
                *(half8*)&sm.x[0][xrow][part * 32 + s2 * 8] = h;
                *(half8*)&sm.x[1][xrow][part * 32 + s2 * 8] = l;
            }
        }
        __syncthreads();
        // ---- MFMA: pass-major, 4 independent acc chains --------------------
        f32x4 acc[2][2];
        acc[0][0] = (f32x4)0.0f; acc[0][1] = (f32x4)0.0f;
        acc[1][0] = (f32x4)0.0f; acc[1][1] = (f32x4)0.0f;
#pragma unroll
        for (int ks = 0; ks < 8; ++ks) {
            half8 xh0 = *(half8*)&sm.x[0][m][ks * 32 + quad * 8];
            half8 xl0 = *(half8*)&sm.x[1][m][ks * 32 + quad * 8];
            half8 xh1 = *(half8*)&sm.x[0][16 + m][ks * 32 + quad * 8];
            half8 xl1 = *(half8*)&sm.x[1][16 + m][ks * 32 + quad * 8];
            acc[0][0] = __builtin_amdgcn_mfma_f32_16x16x32_f16(ql[0][ks], xh0, acc[0][0], 0, 0, 0);
            acc[0][1] = __builtin_amdgcn_mfma_f32_16x16x32_f16(ql[0][ks], xh1, acc[0][1], 0, 0, 0);
            acc[1][0] = __builtin_amdgcn_mfma_f32_16x16x32_f16(ql[1][ks], xh0, acc[1][0], 0, 0, 0);
            acc[1][1] = __builtin_amdgcn_mfma_f32_16x16x32_f16(ql[1][ks], xh1, acc[1][1], 0, 0, 0);
            acc[0][0] = __builtin_amdgcn_mfma_f32_16x16x32_f16(qh[0][ks], xl0, acc[0][0], 0, 0, 0);
            acc[0][1] = __builtin_amdgcn_mfma_f32_16x16x32_f16(qh[0][ks], xl1, acc[0][1], 0, 0, 0);
            acc[1][0] = __builtin_amdgcn_mfma_f32_16x16x32_f16(qh[1][ks], xl0, acc[1][0], 0, 0, 0);
            acc[1][1] = __builtin_amdgcn_mfma_f32_16x16x32_f16(qh[1][ks], xl1, acc[1][1], 0, 0, 0);
            acc[0][0] = __builtin_amdgcn_mfma_f32_16x16x32_f16(qh[0][ks], xh0, acc[0][0], 0, 0, 0);
            acc[0][1] = __builtin_amdgcn_mfma_f32_16x16x32_f16(qh[0][ks], xh1, acc[0][1], 0, 0, 0);
            acc[1][0] = __builtin_amdgcn_mfma_f32_16x16x32_f16(qh[1][ks], xh0, acc[1][0], 0, 0, 0);
            acc[1][1] = __builtin_amdgcn_mfma_f32_16x16x32_f16(qh[1][ks], xh1, acc[1][1], 0, 0, 0);
        }
        __syncthreads();   // all waves done reading x; safe to alias as dt
        // ---- epilogue: d = (qq - 2S) + xx, dump to dt ----------------------
        {
            float xx0 = XX[segbase + ct * 32 + m];
            float xx1 = XX[segbase + ct * 32 + 16 + m];
#pragma unroll
            for (int qs = 0; qs < 2; ++qs) {
                int qb = w * 32 + qs * 16 + quad * 4;
#pragma unroll
                for (int reg = 0; reg < 4; ++reg) {
                    float qq = QQs[qb + reg];
                    sm.dt[qb + reg][m]      = (qq - 2.0f * acc[qs][0][reg]) + xx0;
                    sm.dt[qb + reg][16 + m] = (qq - 2.0f * acc[qs][1][reg]) + xx1;
                }
            }
        }
        __syncthreads();
        // ---- selection: thread t (<128) owns query t, scans 32 candidates --
        if (t < 128) {
            const int ibase = segbase + ct * 32;
            for (int j = 0; j < 32; ++j) {
                float d = sm.dt[t][j];
                if (d < sd[15]) {
                    sd[15] = d; si[15] = ibase + j;   // ascending idx => strict < ok
#pragma unroll
                    for (int r = 15; r > 0; --r) {
                        if (sd[r] < sd[r - 1]) {
                            float td2 = sd[r]; sd[r] = sd[r - 1]; sd[r - 1] = td2;
                            int ti = si[r]; si[r] = si[r - 1]; si[r - 1] = ti;
                        }
                    }
                }
            }
        }
    }
    // ---- write sorted per-segment partial top-16 ---------------------------
    if (t < 128) {
        size_t o = ((size_t)(b * TD_S + qq8 * 128 + t)) * 64 + seg * 16;
#pragma unroll
        for (int r = 0; r < 16; ++r) { PD[o + r] = sd[r]; PI[o + r] = si[r]; }
    }
}

// Exact 4-way merge of sorted segment partials -> final top-16 per query.
__global__ __launch_bounds__(64)
void td_merge(const float* __restrict__ PD, const int* __restrict__ PI,
              int* __restrict__ NN) {
    __shared__ float ld_[64][65];
    __shared__ int   li_[64][65];
    const int bx = blockIdx.x, t = threadIdx.x;
    for (int j = 0; j < 64; ++j) {
        ld_[j][t] = PD[(size_t)bx * 4096 + j * 64 + t];
        li_[j][t] = PI[(size_t)bx * 4096 + j * 64 + t];
    }
    __syncthreads();
    int p[4] = {0, 0, 0, 0};
    int og = (bx * 64 + t) * TD_K;
    for (int r = 0; r < 16; ++r) {
        float bd = __builtin_inff(); int bi = 0x7fffffff; int bs = 0;
#pragma unroll
        for (int s = 0; s < 4; ++s) {
            if (p[s] < 16) {
                float d = ld_[t][s * 16 + p[s]];
                int   i = li_[t][s * 16 + p[s]];
                if (d < bd || (d == bd && i < bi)) { bd = d; bi = i; bs = s; }
            }
        }
        p[bs]++;
        NN[og + r] = bi;
    }
}

// 4 queries per block; cloud-grouped swizzle for L2 locality on H rows.
__global__ __launch_bounds__(256)
void td_maxpool(const unsigned short* __restrict__ H, const int* __restrict__ NN,
                const float* __restrict__ SS, float* __restrict__ outF) {
    __shared__ int nbr[64];
    const int bx = blockIdx.x, t = threadIdx.x;
    const int cloud = bx & 15, blk = bx >> 4;       // 256 blocks per cloud
    const int qbase = cloud * 1024 + blk * 4;
    if (t < 64) nbr[t] = NN[(size_t)qbase * 16 + t];
    __syncthreads();
    float sc0 = SS[2 * t], sc1 = SS[2 * t + 1];
    float sh0 = SS[512 + 2 * t], sh1 = SS[512 + 2 * t + 1];
#pragma unroll
    for (int qi = 0; qi < 4; ++qi) {
        float m0 = 0.0f, m1 = 0.0f;   // relu floor: max_k relu(v) = max(0, max_k v)
#pragma unroll
        for (int k = 0; k < 16; ++k) {
            int row = nbr[qi * 16 + k];
            unsigned u = ((const unsigned*)(H + (size_t)row * 512))[t];
            float lo = __uint_as_float(u << 16);
            float hi = __uint_as_float(u & 0xffff0000u);
            m0 = fmaxf(m0, fmaf(sc0, lo, sh0));
            m1 = fmaxf(m1, fmaf(sc1, hi, sh1));
        }
        float2 o; o.x = m0; o.y = m1;
        *(float2*)&outF[(size_t)(qbase + qi) * 512 + 2 * t] = o;
    }
}

extern "C" void kernel_launch(void* const* d_in, const int* in_sizes, int n_in,
                              void* d_out, int out_size, void* d_ws, size_t ws_size,
                              hipStream_t stream) {
    const float* feat  = (const float*)d_in[0];
    const float* pos   = (const float*)d_in[1];
    // d_in[2] = batch (int32): unused, value is row/P by construction
    const float* W     = (const float*)d_in[3];
    const float* bias  = (const float*)d_in[4];
    const float* gamma = (const float*)d_in[5];
    const float* beta  = (const float*)d_in[6];

    char* ws = (char*)d_ws;
    unsigned short* H = (unsigned short*)ws;            // 67,108,864 B (bf16 h)
    float* XX  = (float*)(ws + 67108864);               //    262,144 B
    int*   FPSI= (int*)  (ws + 67371008);               //     65,536 B
    int*   NN  = (int*)  (ws + 67436544);               //  1,048,576 B
    float* P1  = (float*)(ws + 68485120);               //    524,288 B used
    float* P2  = (float*)(ws + 69533696);               //    524,288 B used
    float* SS  = (float*)(ws + 70582272);               //      4,096 B
    float* PD  = (float*)(ws + 70586368);               //  4,194,304 B
    int*   PI  = (int*)  (ws + 74780672);               //  4,194,304 B

    float* outF = (float*)d_out;
    float* outP = outF + (size_t)TD_B * TD_S * TD_OUTF;   // 8,388,608
    float* outB = outP + (size_t)TD_B * TD_S * 3;         // +49,152

    td_fused  <<<2064, 512, 0, stream>>>(feat, pos, W, bias, H, XX, FPSI, outP, outB);
    td_stats  <<<256, 256, 0, stream>>>(H, P1, P2);
    td_bnfin  <<<1, 512, 0, stream>>>(P1, P2, gamma, beta, SS);
    td_knn2   <<<512, 256, 0, stream>>>(feat, XX, FPSI, PD, PI);
    td_merge  <<<256, 64, 0, stream>>>(PD, PI, NN);
    td_maxpool<<<TD_B * 256, 256, 0, stream>>>(H, NN, SS, outF);
}